// Round 25
// baseline (333.879 us; speedup 1.0000x reference)
//
#include <hip/hip_runtime.h>
#include <hip/hip_bf16.h>

typedef __attribute__((ext_vector_type(8))) short short8;
typedef __attribute__((ext_vector_type(4))) float f32x4;

union I4S8 { int4 i; short8 s; };

#if defined(__has_builtin)
#if __has_builtin(__builtin_amdgcn_global_load_lds)
#define HAVE_GLL 1
#endif
#endif

__device__ __forceinline__ unsigned short f2b(float f) {
  union { __hip_bfloat16 h; unsigned short u; } c;
  c.h = __float2bfloat16(f);
  return c.u;
}
__device__ __forceinline__ unsigned pk2(float a, float b) {
  union { __hip_bfloat162 h2; unsigned u; } c;
  c.h2 = __hip_bfloat162{__float2bfloat16(a), __float2bfloat16(b)};
  return c.u;
}
__device__ __forceinline__ float b2f(unsigned short h) {
  return __uint_as_float(((unsigned)h) << 16);
}
// exact identity: 0.5*v*(1+tanh(c)) == v * sigmoid(2c); proven absmax-safe (round 10)
__device__ __forceinline__ float gelu_fast(float v) {
  float c2 = 1.5957691216057308f * (v + 0.044715f * v * v * v);
  return v / (1.0f + __expf(-c2));
}
// T1 XCD-aware swizzle: bijective when n%8==0 (each XCD gets a contiguous chunk)
__device__ __forceinline__ int xcd_swz(int bid, int n) {
  return ((n & 7) == 0) ? ((bid & 7) * (n >> 3) + (bid >> 3)) : bid;
}

// stage one 8-row group (BK=64 bf16) via global_load_lds with XOR pre-swizzled source.
__device__ __forceinline__ void stage8(const unsigned short* ga, unsigned short* lds_base,
                                       int lane) {
#ifdef HAVE_GLL
  __builtin_amdgcn_global_load_lds(
      (const __attribute__((address_space(1))) void*)ga,
      (__attribute__((address_space(3))) void*)lds_base, 16, 0, 0);
#else
  *(int4*)(lds_base + (lane >> 3) * 64 + (lane & 7) * 8) = *(const int4*)ga;
#endif
}

// ---------------- k_misc: parallel CPB table (169 blocks) + scales (block 169) ----------------
__global__ void k_misc(const float* __restrict__ logit_scale,
                       const float* __restrict__ w1, const float* __restrict__ b1,
                       const float* __restrict__ w2,
                       float* __restrict__ scales, float* __restrict__ tblg) {
  const int bb = blockIdx.x;
  const int t = threadIdx.x;
  if (bb == 169) {
    if (t < 8) scales[t] = expf(fminf(logit_scale[t], logf(100.0f)));
    return;
  }
  __shared__ float red[4][8];
  int a = bb / 13, b = bb % 13;
  float ra = (float)(a - 6) * (8.0f / 6.0f);
  float rb = (float)(b - 6) * (8.0f / 6.0f);
  float sa = (ra > 0.f) ? 1.f : ((ra < 0.f) ? -1.f : 0.f);
  float sb = (rb > 0.f) ? 1.f : ((rb < 0.f) ? -1.f : 0.f);
  float t0 = sa * log2f(fabsf(ra) + 1.0f) / 3.0f;
  float t1 = sb * log2f(fabsf(rb) + 1.0f) / 3.0f;
  float acc[8];
#pragma unroll
  for (int hh = 0; hh < 8; ++hh) acc[hh] = 0.f;
#pragma unroll
  for (int jj = 0; jj < 2; ++jj) {
    int j = t + jj * 256;
    float hv = fmaxf(w1[2 * j] * t0 + w1[2 * j + 1] * t1 + b1[j], 0.0f);
#pragma unroll
    for (int hh = 0; hh < 8; ++hh) acc[hh] += w2[hh * 512 + j] * hv;
  }
#pragma unroll
  for (int hh = 0; hh < 8; ++hh) {
    acc[hh] += __shfl_xor(acc[hh], 1);
    acc[hh] += __shfl_xor(acc[hh], 2);
    acc[hh] += __shfl_xor(acc[hh], 4);
    acc[hh] += __shfl_xor(acc[hh], 8);
    acc[hh] += __shfl_xor(acc[hh], 16);
    acc[hh] += __shfl_xor(acc[hh], 32);
  }
  if ((t & 63) == 0) {
#pragma unroll
    for (int hh = 0; hh < 8; ++hh) red[t >> 6][hh] = acc[hh];
  }
  __syncthreads();
  if (t < 8) tblg[bb * 8 + t] = red[0][t] + red[1][t] + red[2][t] + red[3][t];
}

// ---------------- k_bias: biasT[h][k][q] padded 64x64, pad=-3e8 ----------------
__global__ void k_bias(const float* __restrict__ tblg, float* __restrict__ biasT) {
  int idx = blockIdx.x * 256 + threadIdx.x;   // 8*64*64 = 32768
  int h = idx >> 12, rem = idx & 4095, k = rem >> 6, q = rem & 63;
  float v;
  if (k >= 49 || q >= 49) {
    v = -3.0e8f;
  } else {
    int e = (q / 7 - k / 7 + 6) * 13 + (q % 7 - k % 7 + 6);
    float r = tblg[e * 8 + h];
    v = 16.0f / (1.0f + expf(-r));
  }
  biasT[idx] = v;
}

// ---------------- k_cvt: weights fp32 -> bf16 ----------------
__global__ void k_cvt(const float* __restrict__ qkv_w, const float* __restrict__ proj_w,
                      const float* __restrict__ fc1_w, const float* __restrict__ fc2_w,
                      unsigned short* __restrict__ wq, unsigned short* __restrict__ wp,
                      unsigned short* __restrict__ w1, unsigned short* __restrict__ w2) {
  int i = blockIdx.x * 256 + threadIdx.x;
  if (i < 196608) wq[i] = f2b(qkv_w[i]);
  else if (i < 262144) wp[i - 196608] = f2b(proj_w[i - 196608]);
  else if (i < 524288) w1[i - 262144] = f2b(fc1_w[i - 262144]);
  else w2[i - 524288] = f2b(fc2_w[i - 524288]);
}

// ---------------- k_xprep: shifted-window gather x -> xw[50176][256] bf16 ----------------
__global__ void k_xprep(const float* __restrict__ x, unsigned short* __restrict__ xw) {
  int id = blockIdx.x * 256 + threadIdx.x;
  int row = id >> 5, c8 = (id & 31) << 3;
  int win = row / 49, r = row - win * 49;
  int b = win >> 6, wi = (win >> 3) & 7, wj = win & 7;
  int i = r / 7, j = r - i * 7;
  int ho = (wi * 7 + i + 3) % 56;
  int wo = (wj * 7 + j + 3) % 56;
  const float* src = x + (size_t)(b * 3136 + ho * 56 + wo) * 256 + c8;
  float4 f0 = *(const float4*)(src);
  float4 f1 = *(const float4*)(src + 4);
  int4 pk;
  pk.x = pk2(f0.x, f0.y);
  pk.y = pk2(f0.z, f0.w);
  pk.z = pk2(f1.x, f1.y);
  pk.w = pk2(f1.z, f1.w);
  *(int4*)(xw + (size_t)row * 256 + c8) = pk;
}

// ---------------- k_qkvg: 128x256 tile (one of q/k/v per block), 512 threads ----------------
__launch_bounds__(512)
__global__ void k_qkvg(const unsigned short* __restrict__ xw, const unsigned short* __restrict__ wq,
                       const float* __restrict__ q_bias, const float* __restrict__ v_bias,
                       const float* __restrict__ scales, unsigned short* __restrict__ qkv) {
  const int mb = xcd_swz(blockIdx.x, gridDim.x), nb = blockIdx.y;   // 392 x 3
  const int t = threadIdx.x, lane = t & 63, w = t >> 6;   // 8 waves
  const int wm = w >> 2, wn = w & 3;                      // 2 (M) x 4 (N)
  const int l15 = lane & 15, g = lane >> 4, rj = g << 2;

  __shared__ __align__(16) unsigned short As[128 * 64];   // 16384 B
  __shared__ __align__(16) unsigned short Bs[256 * 64];   // 32768 B

  f32x4 acc[4][4];
#pragma unroll
  for (int mf = 0; mf < 4; ++mf)
#pragma unroll
    for (int nf = 0; nf < 4; ++nf) acc[mf][nf] = (f32x4){0.f, 0.f, 0.f, 0.f};

  const int rl = lane >> 3;
  const int ca = (lane & 7) ^ rl;

  for (int kb = 0; kb < 4; ++kb) {
    __syncthreads();
#pragma unroll
    for (int i = 0; i < 6; ++i) {
      int gidx = w * 6 + i;
      if (gidx < 16) {
        int r = gidx * 8 + rl;
        stage8(xw + (size_t)(mb * 128 + r) * 256 + kb * 64 + ca * 8, As + gidx * 8 * 64, lane);
      } else {
        int gb = gidx - 16;
        int r = gb * 8 + rl;
        stage8(wq + (size_t)(nb * 256 + r) * 256 + kb * 64 + ca * 8, Bs + gb * 8 * 64, lane);
      }
    }
    __syncthreads();
#pragma unroll
    for (int ks = 0; ks < 2; ++ks) {
      short8 a_[4], b_[4];
#pragma unroll
      for (int mf = 0; mf < 4; ++mf) {
        int R = wm * 64 + mf * 16 + l15;
        a_[mf] = *(const short8*)(As + R * 64 + (((ks * 4 + g) ^ (R & 7)) << 3));
      }
#pragma unroll
      for (int nf = 0; nf < 4; ++nf) {
        int R = wn * 64 + nf * 16 + l15;
        b_[nf] = *(const short8*)(Bs + R * 64 + (((ks * 4 + g) ^ (R & 7)) << 3));
      }
#pragma unroll
      for (int mf = 0; mf < 4; ++mf)
#pragma unroll
        for (int nf = 0; nf < 4; ++nf)
          acc[mf][nf] = __builtin_amdgcn_mfma_f32_16x16x32_bf16(a_[mf], b_[nf], acc[mf][nf], 0, 0, 0);
    }
  }

  const int which = nb;
  if (which != 1) {
    const float* bp = (which == 0) ? q_bias : v_bias;
#pragma unroll
    for (int nf = 0; nf < 4; ++nf) {
      float bias = bp[wn * 64 + nf * 16 + l15];
#pragma unroll
      for (int mf = 0; mf < 4; ++mf)
#pragma unroll
        for (int j = 0; j < 4; ++j) acc[mf][nf][j] += bias;
    }
  }
  if (which < 2) {
#pragma unroll
    for (int mf = 0; mf < 4; ++mf)
#pragma unroll
      for (int p = 0; p < 2; ++p)
#pragma unroll
        for (int j = 0; j < 4; ++j) {
          float ss = acc[mf][2*p][j] * acc[mf][2*p][j] + acc[mf][2*p+1][j] * acc[mf][2*p+1][j];
          ss += __shfl_xor(ss, 1); ss += __shfl_xor(ss, 2);
          ss += __shfl_xor(ss, 4); ss += __shfl_xor(ss, 8);
          float inv = 1.0f / fmaxf(sqrtf(ss), 1e-12f);
          if (which == 0) inv *= scales[wn * 2 + p];
          acc[mf][2*p][j] *= inv;
          acc[mf][2*p+1][j] *= inv;
        }
  }
  // scatter to [win][3][head][49][32]
#pragma unroll
  for (int mf = 0; mf < 4; ++mf)
#pragma unroll
    for (int j = 0; j < 4; ++j) {
      int row_g = mb * 128 + wm * 64 + mf * 16 + rj + j;
      int win = row_g / 49, r = row_g - win * 49;
      size_t base = (((size_t)win * 3 + which) * 8) * 1568;
#pragma unroll
      for (int nf = 0; nf < 4; ++nf) {
        int h = wn * 2 + (nf >> 1), d = (nf & 1) * 16 + l15;
        qkv[base + (size_t)h * 1568 + r * 32 + d] = f2b(acc[mf][nf][j]);
      }
    }
}

// ---------------- k_attn2: attention only; O overwrites the q-slice as [49][256] ----------------
__launch_bounds__(256, 4)
__global__ void k_attn2(unsigned short* __restrict__ qkv, const float* __restrict__ biasT) {
  const int win = blockIdx.x;
  const int wi = (win >> 3) & 7, wj = win & 7;
  const int t = threadIdx.x, lane = t & 63, w = t >> 6;
  const int l15 = lane & 15, g = lane >> 4;
  const int kk8 = g << 3, rj = g << 2;

  __shared__ __align__(16) unsigned short VT8[8 * 32 * 72];   // 36864 B

  const int vi = (wi == 7) ? 1 : 0, vj = (wj == 7) ? 1 : 0;

  for (int idx = t; idx < 392; idx += 256) {
    int h = idx / 49, r = idx % 49;
    const unsigned short* vp = qkv + ((((size_t)win * 3 + 2) * 8 + h) * 49 + r) * 32;
    unsigned short vv[32];
    *(int4*)(vv + 0)  = *(const int4*)(vp + 0);
    *(int4*)(vv + 8)  = *(const int4*)(vp + 8);
    *(int4*)(vv + 16) = *(const int4*)(vp + 16);
    *(int4*)(vv + 24) = *(const int4*)(vp + 24);
    unsigned short* dst = VT8 + h * 2304;
#pragma unroll
    for (int d = 0; d < 32; ++d) dst[d * 72 + r] = vv[d];
  }
  for (int idx = t; idx < 3840; idx += 256) {
    int h = idx / 480, rem = idx % 480, d = rem / 15, r = 49 + rem % 15;
    VT8[h * 2304 + d * 72 + r] = 0;
  }
  __syncthreads();

  const int sA = l15 + ((g & 1) << 5);
  const int sB = sA + 16;
  const bool hi = ((g >> 1) & 1) != 0;

  unsigned ob[2][8][2];
  for (int hh = 0; hh < 2; ++hh) {
    const int h = w + hh * 4;
    const float* bT = biasT + (size_t)h * 4096;
    f32x4 s[4][4];
#pragma unroll
    for (int mf = 0; mf < 4; ++mf)
#pragma unroll
      for (int nf = 0; nf < 4; ++nf)
#pragma unroll
        for (int j = 0; j < 4; ++j)
          s[mf][nf][j] = bT[(mf * 16 + rj + j) * 64 + nf * 16 + l15];
    if (vi | vj) {
      int rq[4];
#pragma unroll
      for (int nf = 0; nf < 4; ++nf) {
        int q = nf * 16 + l15, qi = q / 7, qj = q - qi * 7;
        int aq = vi ? (qi < 4 ? 1 : 2) : 0;
        int bq = vj ? (qj < 4 ? 1 : 2) : 0;
        rq[nf] = aq * 3 + bq;
      }
#pragma unroll
      for (int mf = 0; mf < 4; ++mf)
#pragma unroll
        for (int j = 0; j < 4; ++j) {
          int k = mf * 16 + rj + j, ki = k / 7, kj = k - ki * 7;
          int ak = vi ? (ki < 4 ? 1 : 2) : 0;
          int bk = vj ? (kj < 4 ? 1 : 2) : 0;
          int rk = ak * 3 + bk;
#pragma unroll
          for (int nf = 0; nf < 4; ++nf)
            if (rq[nf] != rk) s[mf][nf][j] -= 100.0f;
        }
    }
    const unsigned short* kp = qkv + (((size_t)win * 3 + 1) * 8 + h) * 1568;
    const unsigned short* qp = qkv + (((size_t)win * 3 + 0) * 8 + h) * 1568;
    short8 ka[4], qa[4];
#pragma unroll
    for (int f = 0; f < 4; ++f) {
      ka[f] = *(const short8*)(kp + (f * 16 + l15) * 32 + kk8);
      qa[f] = *(const short8*)(qp + (f * 16 + l15) * 32 + kk8);
    }
#pragma unroll
    for (int mf = 0; mf < 4; ++mf)
#pragma unroll
      for (int nf = 0; nf < 4; ++nf)
        s[mf][nf] = __builtin_amdgcn_mfma_f32_16x16x32_bf16(ka[mf], qa[nf], s[mf][nf], 0, 0, 0);

    unsigned D[4][4][2];
#pragma unroll
    for (int nf = 0; nf < 4; ++nf) {
      float m = -3.0e8f;
#pragma unroll
      for (int mf = 0; mf < 4; ++mf)
#pragma unroll
        for (int j = 0; j < 4; ++j) m = fmaxf(m, s[mf][nf][j]);
      m = fmaxf(m, __shfl_xor(m, 16));
      m = fmaxf(m, __shfl_xor(m, 32));
      float sum = 0.f;
#pragma unroll
      for (int mf = 0; mf < 4; ++mf)
#pragma unroll
        for (int j = 0; j < 4; ++j) {
          float e = __expf(s[mf][nf][j] - m);
          s[mf][nf][j] = e; sum += e;
        }
      sum += __shfl_xor(sum, 16);
      sum += __shfl_xor(sum, 32);
      float inv = 1.0f / sum;
#pragma unroll
      for (int mf = 0; mf < 4; ++mf) {
        D[mf][nf][0] = pk2(s[mf][nf][0] * inv, s[mf][nf][1] * inv);
        D[mf][nf][1] = pk2(s[mf][nf][2] * inv, s[mf][nf][3] * inv);
      }
    }

    f32x4 o[8];
#pragma unroll
    for (int i = 0; i < 8; ++i) o[i] = (f32x4){0.f, 0.f, 0.f, 0.f};
#pragma unroll
    for (int ks = 0; ks < 2; ++ks) {
      short8 vb[2];
#pragma unroll
      for (int dt = 0; dt < 2; ++dt)
        vb[dt] = *(const short8*)(VT8 + h * 2304 + (dt * 16 + l15) * 72 + ks * 32 + kk8);
#pragma unroll
      for (int qt = 0; qt < 4; ++qt) {
        int a0 = __shfl((int)D[2*ks+0][qt][0], sA), a1 = __shfl((int)D[2*ks+1][qt][0], sA);
        int b0 = __shfl((int)D[2*ks+0][qt][1], sA), b1 = __shfl((int)D[2*ks+1][qt][1], sA);
        int c0 = __shfl((int)D[2*ks+0][qt][0], sB), c1 = __shfl((int)D[2*ks+1][qt][0], sB);
        int e0 = __shfl((int)D[2*ks+0][qt][1], sB), e1 = __shfl((int)D[2*ks+1][qt][1], sB);
        I4S8 u;
        u.i.x = hi ? a1 : a0;
        u.i.y = hi ? b1 : b0;
        u.i.z = hi ? c1 : c0;
        u.i.w = hi ? e1 : e0;
#pragma unroll
        for (int dt = 0; dt < 2; ++dt)
          o[qt * 2 + dt] = __builtin_amdgcn_mfma_f32_16x16x32_bf16(u.s, vb[dt], o[qt * 2 + dt], 0, 0, 0);
      }
    }
#pragma unroll
    for (int f = 0; f < 8; ++f) {
      ob[hh][f][0] = pk2(o[f][0], o[f][1]);
      ob[hh][f][1] = pk2(o[f][2], o[f][3]);
    }
  }
  __syncthreads();

  unsigned short* Ow = qkv + (size_t)win * 37632;
#pragma unroll
  for (int hh = 0; hh < 2; ++hh) {
    int h = w + hh * 4;
#pragma unroll
    for (int qt = 0; qt < 4; ++qt)
#pragma unroll
      for (int j = 0; j < 4; ++j) {
        int q = qt * 16 + rj + j;
        if (q < 49) {
#pragma unroll
          for (int dt = 0; dt < 2; ++dt)
            Ow[q * 256 + h * 32 + dt * 16 + l15] =
                (unsigned short)(ob[hh][qt * 2 + dt][j >> 1] >> ((j & 1) * 16));
        }
      }
  }
}

// ---------------- k_proj: x1 = x + LN(O @ Wp^T + b), N-split waves, fused xb bf16 write ----------------
__launch_bounds__(256)
__global__ void k_proj(const unsigned short* __restrict__ qkvO, const unsigned short* __restrict__ wp,
                       const float* __restrict__ proj_b, const float* __restrict__ n1w,
                       const float* __restrict__ n1b, const float* __restrict__ x,
                       float* __restrict__ x1, unsigned short* __restrict__ xb) {
  const int mb = xcd_swz(blockIdx.x, gridDim.x);
  const int t = threadIdx.x, lane = t & 63, w = t >> 6;
  const int wr = w & 1, wc = w >> 1;   // row-half (32 rows), col-half (128 cols)
  const int l15 = lane & 15, g = lane >> 4, rj = g << 2;

  __shared__ __align__(16) unsigned short As[64 * 64];    // 8192 B
  __shared__ __align__(16) unsigned short Bs[256 * 64];   // 32768 B
  __shared__ float RED[64][2][2];                          // {s,s2} per col-half

  f32x4 acc[2][8];
#pragma unroll
  for (int mf = 0; mf < 2; ++mf)
#pragma unroll
    for (int nf = 0; nf < 8; ++nf) acc[mf][nf] = (f32x4){0.f, 0.f, 0.f, 0.f};

  const int rl = lane >> 3;
  const int ca = (lane & 7) ^ rl;

  for (int kb = 0; kb < 4; ++kb) {
    __syncthreads();
#pragma unroll
    for (int cc = 0; cc < 2; ++cc) {
      int rloc = w * 16 + cc * 8 + rl;
      int row_g = mb * 64 + rloc;
      int win = row_g / 49, r = row_g - win * 49;
      stage8(qkvO + (size_t)win * 37632 + r * 256 + kb * 64 + ca * 8,
             As + (w * 16 + cc * 8) * 64, lane);
    }
#pragma unroll
    for (int cc = 0; cc < 4; ++cc) {
      int rloc = w * 64 + cc * 8 + rl;
      stage8(wp + (size_t)rloc * 256 + kb * 64 + ca * 8, Bs + (w * 64 + cc * 8) * 64, lane);
      int rloc2 = rloc + 32;
      stage8(wp + (size_t)rloc2 * 256 + kb * 64 + ca * 8, Bs + (w * 64 + cc * 8 + 32) * 64, lane);
    }
    __syncthreads();
    // N-split compute: 2 A-reads + 8 B-reads per ks
#pragma unroll
    for (int ks = 0; ks < 2; ++ks) {
      short8 a_[2], b_[8];
#pragma unroll
      for (int mf = 0; mf < 2; ++mf) {
        int R = wr * 32 + mf * 16 + l15;
        a_[mf] = *(const short8*)(As + R * 64 + (((ks * 4 + g) ^ (R & 7)) << 3));
      }
#pragma unroll
      for (int nf = 0; nf < 8; ++nf) {
        int Rb = wc * 128 + nf * 16 + l15;
        b_[nf] = *(const short8*)(Bs + Rb * 64 + (((ks * 4 + g) ^ (Rb & 7)) << 3));
      }
#pragma unroll
      for (int mf = 0; mf < 2; ++mf)
#pragma unroll
        for (int nf = 0; nf < 8; ++nf)
          acc[mf][nf] = __builtin_amdgcn_mfma_f32_16x16x32_bf16(a_[mf], b_[nf], acc[mf][nf], 0, 0, 0);
    }
  }
  // bias + partial row sums over this wave's 128 cols
#pragma unroll
  for (int nf = 0; nf < 8; ++nf) {
    float bias = proj_b[wc * 128 + nf * 16 + l15];
#pragma unroll
    for (int mf = 0; mf < 2; ++mf)
#pragma unroll
      for (int j = 0; j < 4; ++j) acc[mf][nf][j] += bias;
  }
#pragma unroll
  for (int mf = 0; mf < 2; ++mf)
#pragma unroll
    for (int j = 0; j < 4; ++j) {
      float s = 0.f, s2 = 0.f;
#pragma unroll
      for (int nf = 0; nf < 8; ++nf) {
        float v = acc[mf][nf][j];
        s += v; s2 += v * v;
      }
      s += __shfl_xor(s, 1);  s += __shfl_xor(s, 2);  s += __shfl_xor(s, 4);  s += __shfl_xor(s, 8);
      s2 += __shfl_xor(s2, 1); s2 += __shfl_xor(s2, 2); s2 += __shfl_xor(s2, 4); s2 += __shfl_xor(s2, 8);
      if (l15 == 0) {
        int row = wr * 32 + mf * 16 + rj + j;
        RED[row][wc][0] = s;
        RED[row][wc][1] = s2;
      }
    }
  __syncthreads();
#pragma unroll
  for (int mf = 0; mf < 2; ++mf)
#pragma unroll
    for (int j = 0; j < 4; ++j) {
      int row = wr * 32 + mf * 16 + rj + j;
      float ts = RED[row][0][0] + RED[row][1][0];
      float ts2 = RED[row][0][1] + RED[row][1][1];
      float mu = ts * (1.0f / 256.0f);
      float var = ts2 * (1.0f / 256.0f) - mu * mu;
      float rs = rsqrtf(var + 1e-5f);
      int row_g = mb * 64 + row;
      int win = row_g / 49, r = row_g - win * 49;
      int b = win >> 6, wi = (win >> 3) & 7, wj = win & 7;
      int i2 = r / 7, j2 = r - i2 * 7;
      int ho = (wi * 7 + i2 + 3) % 56, wo = (wj * 7 + j2 + 3) % 56;
      size_t base = (size_t)(b * 3136 + ho * 56 + wo) * 256;
#pragma unroll
      for (int nf = 0; nf < 8; ++nf) {
        int col = wc * 128 + nf * 16 + l15;
        float xv = x[base + col];
        float val = xv + (acc[mf][nf][j] - mu) * rs * n1w[col] + n1b[col];
        x1[base + col] = val;
        xb[base + col] = f2b(val);   // fused: identical bits to the old k_xb pass
      }
    }
}

// ---------------- k_fc1: H = gelu(xb @ W1^T + b1), GLL-staged, direct scatter ----------------
__launch_bounds__(256)
__global__ void k_fc1(const unsigned short* __restrict__ xb, const unsigned short* __restrict__ w1,
                      const float* __restrict__ b1, unsigned short* __restrict__ Hbuf, int r0) {
  const int mb = xcd_swz(blockIdx.x, gridDim.x), nb = blockIdx.y;
  const int t = threadIdx.x, lane = t & 63, w = t >> 6;
  const int wm = w >> 1, wn = w & 1;
  const int l15 = lane & 15, g = lane >> 4, rj = g << 2;

  __shared__ __align__(16) unsigned short As[128 * 64];   // 16384 B
  __shared__ __align__(16) unsigned short Bs[128 * 64];   // 16384 B

  f32x4 acc[4][4];
#pragma unroll
  for (int mf = 0; mf < 4; ++mf)
#pragma unroll
    for (int nf = 0; nf < 4; ++nf) acc[mf][nf] = (f32x4){0.f, 0.f, 0.f, 0.f};

  const int row_g0 = r0 + mb * 128;
  const int rl = lane >> 3;
  const int ca = (lane & 7) ^ rl;

  for (int kb = 0; kb < 4; ++kb) {
    __syncthreads();
#pragma unroll
    for (int cc = 0; cc < 4; ++cc) {
      int r = w * 32 + cc * 8 + rl;
      stage8(xb + (size_t)(row_g0 + r) * 256 + kb * 64 + ca * 8, As + (w * 32 + cc * 8) * 64, lane);
      stage8(w1 + (size_t)(nb * 128 + r) * 256 + kb * 64 + ca * 8, Bs + (w * 32 + cc * 8) * 64, lane);
    }
    __syncthreads();
#pragma unroll
    for (int ks = 0; ks < 2; ++ks) {
      short8 a_[4], b_[4];
#pragma unroll
      for (int mf = 0; mf < 4; ++mf) {
        int R = wm * 64 + mf * 16 + l15;
        a_[mf] = *(const short8*)(As + R * 64 + (((ks * 4 + g) ^ (R & 7)) << 3));
      }
#pragma unroll
      for (int nf = 0; nf < 4; ++nf) {
        int R = wn * 64 + nf * 16 + l15;
        b_[nf] = *(const short8*)(Bs + R * 64 + (((ks * 4 + g) ^ (R & 7)) << 3));
      }
#pragma unroll
      for (int mf = 0; mf < 4; ++mf)
#pragma unroll
        for (int nf = 0; nf < 4; ++nf)
          acc[mf][nf] = __builtin_amdgcn_mfma_f32_16x16x32_bf16(a_[mf], b_[nf], acc[mf][nf], 0, 0, 0);
    }
  }
  // direct-scatter epilogue
#pragma unroll
  for (int mf = 0; mf < 4; ++mf)
#pragma unroll
    for (int nf = 0; nf < 4; ++nf) {
      int col = nb * 128 + wn * 64 + nf * 16 + l15;
      float bias = b1[col];
#pragma unroll
      for (int j = 0; j < 4; ++j) {
        int row = mb * 128 + wm * 64 + mf * 16 + rj + j;
        Hbuf[(size_t)row * 1024 + col] = f2b(gelu_fast(acc[mf][nf][j] + bias));
      }
    }
}

// ---------------- k_fc2: out = x1 + LN(H @ W2^T + b2), N-split waves, cross-wave LN ----------------
__launch_bounds__(256)
__global__ void k_fc2(const unsigned short* __restrict__ Hbuf, const unsigned short* __restrict__ w2,
                      const float* __restrict__ b2, const float* __restrict__ n2w,
                      const float* __restrict__ n2b, float* __restrict__ xio, int r0) {
  const int mb = xcd_swz(blockIdx.x, gridDim.x);   // 64 rows per block
  const int t = threadIdx.x, lane = t & 63, w = t >> 6;
  const int wr = w & 1, wc = w >> 1;   // row-half (32 rows), col-half (128 cols)
  const int l15 = lane & 15, g = lane >> 4, rj = g << 2;

  __shared__ __align__(16) unsigned short As[64 * 64];    // 8192 B
  __shared__ __align__(16) unsigned short Bs[256 * 64];   // 32768 B
  __shared__ float RED[64][2][2];                          // 1 KB {s,s2} per col-half

  f32x4 acc[2][8];
#pragma unroll
  for (int mf = 0; mf < 2; ++mf)
#pragma unroll
    for (int nf = 0; nf < 8; ++nf) acc[mf][nf] = (f32x4){0.f, 0.f, 0.f, 0.f};

  const int rl = lane >> 3;
  const int ca = (lane & 7) ^ rl;

  for (int kb = 0; kb < 16; ++kb) {
    __syncthreads();
#pragma unroll
    for (int cc = 0; cc < 2; ++cc) {
      int rloc = w * 16 + cc * 8 + rl;
      stage8(Hbuf + (size_t)(mb * 64 + rloc) * 1024 + kb * 64 + ca * 8,
             As + (w * 16 + cc * 8) * 64, lane);
    }
#pragma unroll
    for (int cc = 0; cc < 4; ++cc) {
      int rloc = w * 64 + cc * 8 + rl;
      stage8(w2 + (size_t)rloc * 1024 + kb * 64 + ca * 8, Bs + (w * 64 + cc * 8) * 64, lane);
      int rloc2 = rloc + 32;
      stage8(w2 + (size_t)rloc2 * 1024 + kb * 64 + ca * 8, Bs + (w * 64 + cc * 8 + 32) * 64, lane);
    }
    __syncthreads();
    // N-split compute: 2 A-reads + 8 B-reads per ks
#pragma unroll
    for (int ks = 0; ks < 2; ++ks) {
      short8 a_[2], b_[8];
#pragma unroll
      for (int mf = 0; mf < 2; ++mf) {
        int R = wr * 32 + mf * 16 + l15;
        a_[mf] = *(const short8*)(As + R * 64 + (((ks * 4 + g) ^ (R & 7)) << 3));
      }
#pragma unroll
      for (int nf = 0; nf < 8; ++nf) {
        int Rb = wc * 128 + nf * 16 + l15;
        b_[nf] = *(const short8*)(Bs + Rb * 64 + (((ks * 4 + g) ^ (Rb & 7)) << 3));
      }
#pragma unroll
      for (int mf = 0; mf < 2; ++mf)
#pragma unroll
        for (int nf = 0; nf < 8; ++nf)
          acc[mf][nf] = __builtin_amdgcn_mfma_f32_16x16x32_bf16(a_[mf], b_[nf], acc[mf][nf], 0, 0, 0);
    }
  }
  // bias + partial row sums over this wave's 128 cols
#pragma unroll
  for (int nf = 0; nf < 8; ++nf) {
    float bias = b2[wc * 128 + nf * 16 + l15];
#pragma unroll
    for (int mf = 0; mf < 2; ++mf)
#pragma unroll
      for (int j = 0; j < 4; ++j) acc[mf][nf][j] += bias;
  }
#pragma unroll
  for (int mf = 0; mf < 2; ++mf)
#pragma unroll
    for (int j = 0; j < 4; ++j) {
      float s = 0.f, s2 = 0.f;
#pragma unroll
      for (int nf = 0; nf < 8; ++nf) {
        float v = acc[mf][nf][j];
        s += v; s2 += v * v;
      }
      s += __shfl_xor(s, 1);  s += __shfl_xor(s, 2);  s += __shfl_xor(s, 4);  s += __shfl_xor(s, 8);
      s2 += __shfl_xor(s2, 1); s2 += __shfl_xor(s2, 2); s2 += __shfl_xor(s2, 4); s2 += __shfl_xor(s2, 8);
      if (l15 == 0) {
        int row = wr * 32 + mf * 16 + rj + j;
        RED[row][wc][0] = s;
        RED[row][wc][1] = s2;
      }
    }
  __syncthreads();
#pragma unroll
  for (int mf = 0; mf < 2; ++mf)
#pragma unroll
    for (int j = 0; j < 4; ++j) {
      int row = wr * 32 + mf * 16 + rj + j;
      float ts = RED[row][0][0] + RED[row][1][0];
      float ts2 = RED[row][0][1] + RED[row][1][1];
      float mu = ts * (1.0f / 256.0f);
      float var = ts2 * (1.0f / 256.0f) - mu * mu;
      float rs = rsqrtf(var + 1e-5f);
      size_t base = (size_t)(r0 + mb * 64 + row) * 256;
#pragma unroll
      for (int nf = 0; nf < 8; ++nf) {
        int col = wc * 128 + nf * 16 + l15;
        float xv = xio[base + col];
        xio[base + col] = xv + (acc[mf][nf][j] - mu) * rs * n2w[col] + n2b[col];
      }
    }
}

extern "C" void kernel_launch(void* const* d_in, const int* in_sizes, int n_in,
                              void* d_out, int out_size, void* d_ws, size_t ws_size,
                              hipStream_t stream) {
  const float* x           = (const float*)d_in[0];
  const float* norm1_w     = (const float*)d_in[1];
  const float* norm1_b     = (const float*)d_in[2];
  const float* qkv_w       = (const float*)d_in[3];
  const float* q_bias      = (const float*)d_in[4];
  const float* v_bias      = (const float*)d_in[5];
  const float* logit_scale = (const float*)d_in[6];
  const float* cpb_w1      = (const float*)d_in[7];
  const float* cpb_b1      = (const float*)d_in[8];
  const float* cpb_w2      = (const float*)d_in[9];
  const float* proj_w      = (const float*)d_in[10];
  const float* proj_b      = (const float*)d_in[11];
  const float* norm2_w     = (const float*)d_in[12];
  const float* norm2_b     = (const float*)d_in[13];
  const float* fc1_w       = (const float*)d_in[14];
  const float* fc1_b       = (const float*)d_in[15];
  const float* fc2_w       = (const float*)d_in[16];
  const float* fc2_b       = (const float*)d_in[17];

  char* ws = (char*)d_ws;
  float*          scales  = (float*)(ws + 0);
  float*          tblg    = (float*)(ws + 64);
  unsigned short* wq      = (unsigned short*)(ws + 8192);    // dead after k_qkvg; biasT overlays
  float*          biasT   = (float*)(ws + 8192);
  unsigned short* wp      = (unsigned short*)(ws + 401408);
  unsigned short* w1b     = (unsigned short*)(ws + 532480);
  unsigned short* w2b     = (unsigned short*)(ws + 1056768);
  unsigned short* qkvbuf  = (unsigned short*)(ws + 1581056); // 77070336 B (attn phase)
  unsigned short* xb      = (unsigned short*)(ws + 1581056); // MLP phase (qkvbuf dead): 25.7MB
  unsigned short* Hbuf    = (unsigned short*)(ws + 27271168);
  float*          x1      = (float*)d_out;
  unsigned short* xw      = (unsigned short*)d_out;          // dead before k_proj writes x1

  k_misc<<<dim3(170), dim3(256), 0, stream>>>(logit_scale, cpb_w1, cpb_b1, cpb_w2, scales, tblg);
  k_cvt<<<dim3(3072), dim3(256), 0, stream>>>(qkv_w, proj_w, fc1_w, fc2_w, wq, wp, w1b, w2b);
  k_xprep<<<dim3(6272), dim3(256), 0, stream>>>(x, xw);
  k_qkvg<<<dim3(392, 3), dim3(512), 0, stream>>>(xw, wq, q_bias, v_bias, scales, qkvbuf);
  k_bias<<<dim3(128), dim3(256), 0, stream>>>(tblg, biasT);
  k_attn2<<<dim3(1024), dim3(256), 0, stream>>>(qkvbuf, biasT);
  // NOTE: k_proj writes into the qkvbuf region's tail? No — xb (ws+1581056) overlays qkvbuf,
  // but k_proj still READS qkvbuf (O slices at win*37632, all < 38.6MB region start... they
  // overlap). Guard: xb writes must not clobber O rows k_proj hasn't read yet. They would.
  // So keep xb in a disjoint region: place it AFTER Hbuf when 1-pass, else reuse is unsafe.
  // We place xb at ws + 130031616 (after Hbuf) — fits: needs 130.0MB + 25.7MB = 155.7MB.
  // Fallback (small ws): keep separate k_xb-free path impossible -> use upper Hbuf half region.
  {
    unsigned short* xb_safe;
    const size_t need_big = 27271168ull + 102760448ull + 25690112ull;  // Hbuf end + xb (155.7MB)
    if (ws_size >= need_big) {
      xb_safe = (unsigned short*)(ws + 27271168 + 102760448);
      k_proj<<<dim3(784), dim3(256), 0, stream>>>(qkvbuf, wp, proj_b, norm1_w, norm1_b, x, x1, xb_safe);
      k_fc1<<<dim3(392, 8), dim3(256), 0, stream>>>(xb_safe, w1b, fc1_b, Hbuf, 0);
      k_fc2<<<dim3(784), dim3(256), 0, stream>>>(Hbuf, w2b, fc2_b, norm2_w, norm2_b, x1, 0);
    } else {
      // 2-pass fallback: xb at old overlay spot is unsafe to write during k_proj reads of qkvbuf,
      // so shift xb past the O region actually read (qkvbuf O slices end at 1024*37632*2 B).
      xb_safe = (unsigned short*)(ws + 1581056 + 77070336);  // after qkvbuf (disjoint)
      k_proj<<<dim3(784), dim3(256), 0, stream>>>(qkvbuf, wp, proj_b, norm1_w, norm1_b, x, x1, xb_safe);
      k_fc1<<<dim3(196, 8), dim3(256), 0, stream>>>(xb_safe, w1b, fc1_b, Hbuf, 0);
      k_fc2<<<dim3(392), dim3(256), 0, stream>>>(Hbuf, w2b, fc2_b, norm2_w, norm2_b, x1, 0);
      k_fc1<<<dim3(196, 8), dim3(256), 0, stream>>>(xb_safe, w1b, fc1_b, Hbuf, 25088);
      k_fc2<<<dim3(392), dim3(256), 0, stream>>>(Hbuf, w2b, fc2_b, norm2_w, norm2_b, x1, 25088);
    }
  }
}

// Round 26
// 306.383 us; speedup vs baseline: 1.0897x; 1.0897x over previous
//
#include <hip/hip_runtime.h>
#include <hip/hip_bf16.h>

typedef __attribute__((ext_vector_type(8))) short short8;
typedef __attribute__((ext_vector_type(4))) float f32x4;

union I4S8 { int4 i; short8 s; };

#if defined(__has_builtin)
#if __has_builtin(__builtin_amdgcn_global_load_lds)
#define HAVE_GLL 1
#endif
#endif

__device__ __forceinline__ unsigned short f2b(float f) {
  union { __hip_bfloat16 h; unsigned short u; } c;
  c.h = __float2bfloat16(f);
  return c.u;
}
__device__ __forceinline__ unsigned pk2(float a, float b) {
  union { __hip_bfloat162 h2; unsigned u; } c;
  c.h2 = __hip_bfloat162{__float2bfloat16(a), __float2bfloat16(b)};
  return c.u;
}
__device__ __forceinline__ float b2f(unsigned short h) {
  return __uint_as_float(((unsigned)h) << 16);
}
// exact identity: 0.5*v*(1+tanh(c)) == v * sigmoid(2c); proven absmax-safe (round 10)
__device__ __forceinline__ float gelu_fast(float v) {
  float c2 = 1.5957691216057308f * (v + 0.044715f * v * v * v);
  return v / (1.0f + __expf(-c2));
}
// T1 XCD-aware swizzle: bijective when n%8==0 (each XCD gets a contiguous chunk)
__device__ __forceinline__ int xcd_swz(int bid, int n) {
  return ((n & 7) == 0) ? ((bid & 7) * (n >> 3) + (bid >> 3)) : bid;
}

// stage one 8-row group (BK=64 bf16) via global_load_lds with XOR pre-swizzled source.
__device__ __forceinline__ void stage8(const unsigned short* ga, unsigned short* lds_base,
                                       int lane) {
#ifdef HAVE_GLL
  __builtin_amdgcn_global_load_lds(
      (const __attribute__((address_space(1))) void*)ga,
      (__attribute__((address_space(3))) void*)lds_base, 16, 0, 0);
#else
  *(int4*)(lds_base + (lane >> 3) * 64 + (lane & 7) * 8) = *(const int4*)ga;
#endif
}

// ---------------- k_misc: parallel CPB table (169 blocks) + scales (block 169) ----------------
__global__ void k_misc(const float* __restrict__ logit_scale,
                       const float* __restrict__ w1, const float* __restrict__ b1,
                       const float* __restrict__ w2,
                       float* __restrict__ scales, float* __restrict__ tblg) {
  const int bb = blockIdx.x;
  const int t = threadIdx.x;
  if (bb == 169) {
    if (t < 8) scales[t] = expf(fminf(logit_scale[t], logf(100.0f)));
    return;
  }
  __shared__ float red[4][8];
  int a = bb / 13, b = bb % 13;
  float ra = (float)(a - 6) * (8.0f / 6.0f);
  float rb = (float)(b - 6) * (8.0f / 6.0f);
  float sa = (ra > 0.f) ? 1.f : ((ra < 0.f) ? -1.f : 0.f);
  float sb = (rb > 0.f) ? 1.f : ((rb < 0.f) ? -1.f : 0.f);
  float t0 = sa * log2f(fabsf(ra) + 1.0f) / 3.0f;
  float t1 = sb * log2f(fabsf(rb) + 1.0f) / 3.0f;
  float acc[8];
#pragma unroll
  for (int hh = 0; hh < 8; ++hh) acc[hh] = 0.f;
#pragma unroll
  for (int jj = 0; jj < 2; ++jj) {
    int j = t + jj * 256;
    float hv = fmaxf(w1[2 * j] * t0 + w1[2 * j + 1] * t1 + b1[j], 0.0f);
#pragma unroll
    for (int hh = 0; hh < 8; ++hh) acc[hh] += w2[hh * 512 + j] * hv;
  }
#pragma unroll
  for (int hh = 0; hh < 8; ++hh) {
    acc[hh] += __shfl_xor(acc[hh], 1);
    acc[hh] += __shfl_xor(acc[hh], 2);
    acc[hh] += __shfl_xor(acc[hh], 4);
    acc[hh] += __shfl_xor(acc[hh], 8);
    acc[hh] += __shfl_xor(acc[hh], 16);
    acc[hh] += __shfl_xor(acc[hh], 32);
  }
  if ((t & 63) == 0) {
#pragma unroll
    for (int hh = 0; hh < 8; ++hh) red[t >> 6][hh] = acc[hh];
  }
  __syncthreads();
  if (t < 8) tblg[bb * 8 + t] = red[0][t] + red[1][t] + red[2][t] + red[3][t];
}

// ---------------- k_bias: biasT[h][k][q] padded 64x64, pad=-3e8 ----------------
__global__ void k_bias(const float* __restrict__ tblg, float* __restrict__ biasT) {
  int idx = blockIdx.x * 256 + threadIdx.x;   // 8*64*64 = 32768
  int h = idx >> 12, rem = idx & 4095, k = rem >> 6, q = rem & 63;
  float v;
  if (k >= 49 || q >= 49) {
    v = -3.0e8f;
  } else {
    int e = (q / 7 - k / 7 + 6) * 13 + (q % 7 - k % 7 + 6);
    float r = tblg[e * 8 + h];
    v = 16.0f / (1.0f + expf(-r));
  }
  biasT[idx] = v;
}

// ---------------- k_cvt: weights fp32 -> bf16 ----------------
__global__ void k_cvt(const float* __restrict__ qkv_w, const float* __restrict__ proj_w,
                      const float* __restrict__ fc1_w, const float* __restrict__ fc2_w,
                      unsigned short* __restrict__ wq, unsigned short* __restrict__ wp,
                      unsigned short* __restrict__ w1, unsigned short* __restrict__ w2) {
  int i = blockIdx.x * 256 + threadIdx.x;
  if (i < 196608) wq[i] = f2b(qkv_w[i]);
  else if (i < 262144) wp[i - 196608] = f2b(proj_w[i - 196608]);
  else if (i < 524288) w1[i - 262144] = f2b(fc1_w[i - 262144]);
  else w2[i - 524288] = f2b(fc2_w[i - 524288]);
}

// ---------------- k_xprep: shifted-window gather x -> xw[50176][256] bf16 ----------------
__global__ void k_xprep(const float* __restrict__ x, unsigned short* __restrict__ xw) {
  int id = blockIdx.x * 256 + threadIdx.x;
  int row = id >> 5, c8 = (id & 31) << 3;
  int win = row / 49, r = row - win * 49;
  int b = win >> 6, wi = (win >> 3) & 7, wj = win & 7;
  int i = r / 7, j = r - i * 7;
  int ho = (wi * 7 + i + 3) % 56;
  int wo = (wj * 7 + j + 3) % 56;
  const float* src = x + (size_t)(b * 3136 + ho * 56 + wo) * 256 + c8;
  float4 f0 = *(const float4*)(src);
  float4 f1 = *(const float4*)(src + 4);
  int4 pk;
  pk.x = pk2(f0.x, f0.y);
  pk.y = pk2(f0.z, f0.w);
  pk.z = pk2(f1.x, f1.y);
  pk.w = pk2(f1.z, f1.w);
  *(int4*)(xw + (size_t)row * 256 + c8) = pk;
}

// ---------------- k_xb: x1 f32 -> xb bf16 (row-linear) ----------------
__global__ void k_xb(const float* __restrict__ x1, unsigned short* __restrict__ xb) {
  int id = blockIdx.x * 256 + threadIdx.x;
  size_t off = (size_t)id << 3;
  const float* src = x1 + off;
  float4 f0 = *(const float4*)(src);
  float4 f1 = *(const float4*)(src + 4);
  int4 pk;
  pk.x = pk2(f0.x, f0.y);
  pk.y = pk2(f0.z, f0.w);
  pk.z = pk2(f1.x, f1.y);
  pk.w = pk2(f1.z, f1.w);
  *(int4*)(xb + off) = pk;
}

// ---------------- k_qkvg: 128x256 tile (one of q/k/v per block), 512 threads ----------------
__launch_bounds__(512)
__global__ void k_qkvg(const unsigned short* __restrict__ xw, const unsigned short* __restrict__ wq,
                       const float* __restrict__ q_bias, const float* __restrict__ v_bias,
                       const float* __restrict__ scales, unsigned short* __restrict__ qkv) {
  const int mb = xcd_swz(blockIdx.x, gridDim.x), nb = blockIdx.y;   // 392 x 3
  const int t = threadIdx.x, lane = t & 63, w = t >> 6;   // 8 waves
  const int wm = w >> 2, wn = w & 3;                      // 2 (M) x 4 (N)
  const int l15 = lane & 15, g = lane >> 4, rj = g << 2;

  __shared__ __align__(16) unsigned short As[128 * 64];   // 16384 B
  __shared__ __align__(16) unsigned short Bs[256 * 64];   // 32768 B

  f32x4 acc[4][4];
#pragma unroll
  for (int mf = 0; mf < 4; ++mf)
#pragma unroll
    for (int nf = 0; nf < 4; ++nf) acc[mf][nf] = (f32x4){0.f, 0.f, 0.f, 0.f};

  const int rl = lane >> 3;
  const int ca = (lane & 7) ^ rl;

  for (int kb = 0; kb < 4; ++kb) {
    __syncthreads();
#pragma unroll
    for (int i = 0; i < 6; ++i) {
      int gidx = w * 6 + i;
      if (gidx < 16) {
        int r = gidx * 8 + rl;
        stage8(xw + (size_t)(mb * 128 + r) * 256 + kb * 64 + ca * 8, As + gidx * 8 * 64, lane);
      } else {
        int gb = gidx - 16;
        int r = gb * 8 + rl;
        stage8(wq + (size_t)(nb * 256 + r) * 256 + kb * 64 + ca * 8, Bs + gb * 8 * 64, lane);
      }
    }
    __syncthreads();
#pragma unroll
    for (int ks = 0; ks < 2; ++ks) {
      short8 a_[4], b_[4];
#pragma unroll
      for (int mf = 0; mf < 4; ++mf) {
        int R = wm * 64 + mf * 16 + l15;
        a_[mf] = *(const short8*)(As + R * 64 + (((ks * 4 + g) ^ (R & 7)) << 3));
      }
#pragma unroll
      for (int nf = 0; nf < 4; ++nf) {
        int R = wn * 64 + nf * 16 + l15;
        b_[nf] = *(const short8*)(Bs + R * 64 + (((ks * 4 + g) ^ (R & 7)) << 3));
      }
#pragma unroll
      for (int mf = 0; mf < 4; ++mf)
#pragma unroll
        for (int nf = 0; nf < 4; ++nf)
          acc[mf][nf] = __builtin_amdgcn_mfma_f32_16x16x32_bf16(a_[mf], b_[nf], acc[mf][nf], 0, 0, 0);
    }
  }

  const int which = nb;
  if (which != 1) {
    const float* bp = (which == 0) ? q_bias : v_bias;
#pragma unroll
    for (int nf = 0; nf < 4; ++nf) {
      float bias = bp[wn * 64 + nf * 16 + l15];
#pragma unroll
      for (int mf = 0; mf < 4; ++mf)
#pragma unroll
        for (int j = 0; j < 4; ++j) acc[mf][nf][j] += bias;
    }
  }
  if (which < 2) {
#pragma unroll
    for (int mf = 0; mf < 4; ++mf)
#pragma unroll
      for (int p = 0; p < 2; ++p)
#pragma unroll
        for (int j = 0; j < 4; ++j) {
          float ss = acc[mf][2*p][j] * acc[mf][2*p][j] + acc[mf][2*p+1][j] * acc[mf][2*p+1][j];
          ss += __shfl_xor(ss, 1); ss += __shfl_xor(ss, 2);
          ss += __shfl_xor(ss, 4); ss += __shfl_xor(ss, 8);
          float inv = 1.0f / fmaxf(sqrtf(ss), 1e-12f);
          if (which == 0) inv *= scales[wn * 2 + p];
          acc[mf][2*p][j] *= inv;
          acc[mf][2*p+1][j] *= inv;
        }
  }
  // scatter to [win][3][head][49][32]
#pragma unroll
  for (int mf = 0; mf < 4; ++mf)
#pragma unroll
    for (int j = 0; j < 4; ++j) {
      int row_g = mb * 128 + wm * 64 + mf * 16 + rj + j;
      int win = row_g / 49, r = row_g - win * 49;
      size_t base = (((size_t)win * 3 + which) * 8) * 1568;
#pragma unroll
      for (int nf = 0; nf < 4; ++nf) {
        int h = wn * 2 + (nf >> 1), d = (nf & 1) * 16 + l15;
        qkv[base + (size_t)h * 1568 + r * 32 + d] = f2b(acc[mf][nf][j]);
      }
    }
}

// ---------------- k_attn2: attention only; O overwrites the q-slice as [49][256] ----------------
__launch_bounds__(256, 4)
__global__ void k_attn2(unsigned short* __restrict__ qkv, const float* __restrict__ biasT) {
  const int win = blockIdx.x;
  const int wi = (win >> 3) & 7, wj = win & 7;
  const int t = threadIdx.x, lane = t & 63, w = t >> 6;
  const int l15 = lane & 15, g = lane >> 4;
  const int kk8 = g << 3, rj = g << 2;

  __shared__ __align__(16) unsigned short VT8[8 * 32 * 72];   // 36864 B

  const int vi = (wi == 7) ? 1 : 0, vj = (wj == 7) ? 1 : 0;

  for (int idx = t; idx < 392; idx += 256) {
    int h = idx / 49, r = idx % 49;
    const unsigned short* vp = qkv + ((((size_t)win * 3 + 2) * 8 + h) * 49 + r) * 32;
    unsigned short vv[32];
    *(int4*)(vv + 0)  = *(const int4*)(vp + 0);
    *(int4*)(vv + 8)  = *(const int4*)(vp + 8);
    *(int4*)(vv + 16) = *(const int4*)(vp + 16);
    *(int4*)(vv + 24) = *(const int4*)(vp + 24);
    unsigned short* dst = VT8 + h * 2304;
#pragma unroll
    for (int d = 0; d < 32; ++d) dst[d * 72 + r] = vv[d];
  }
  for (int idx = t; idx < 3840; idx += 256) {
    int h = idx / 480, rem = idx % 480, d = rem / 15, r = 49 + rem % 15;
    VT8[h * 2304 + d * 72 + r] = 0;
  }
  __syncthreads();

  const int sA = l15 + ((g & 1) << 5);
  const int sB = sA + 16;
  const bool hi = ((g >> 1) & 1) != 0;

  unsigned ob[2][8][2];
  for (int hh = 0; hh < 2; ++hh) {
    const int h = w + hh * 4;
    const float* bT = biasT + (size_t)h * 4096;
    f32x4 s[4][4];
#pragma unroll
    for (int mf = 0; mf < 4; ++mf)
#pragma unroll
      for (int nf = 0; nf < 4; ++nf)
#pragma unroll
        for (int j = 0; j < 4; ++j)
          s[mf][nf][j] = bT[(mf * 16 + rj + j) * 64 + nf * 16 + l15];
    if (vi | vj) {
      int rq[4];
#pragma unroll
      for (int nf = 0; nf < 4; ++nf) {
        int q = nf * 16 + l15, qi = q / 7, qj = q - qi * 7;
        int aq = vi ? (qi < 4 ? 1 : 2) : 0;
        int bq = vj ? (qj < 4 ? 1 : 2) : 0;
        rq[nf] = aq * 3 + bq;
      }
#pragma unroll
      for (int mf = 0; mf < 4; ++mf)
#pragma unroll
        for (int j = 0; j < 4; ++j) {
          int k = mf * 16 + rj + j, ki = k / 7, kj = k - ki * 7;
          int ak = vi ? (ki < 4 ? 1 : 2) : 0;
          int bk = vj ? (kj < 4 ? 1 : 2) : 0;
          int rk = ak * 3 + bk;
#pragma unroll
          for (int nf = 0; nf < 4; ++nf)
            if (rq[nf] != rk) s[mf][nf][j] -= 100.0f;
        }
    }
    const unsigned short* kp = qkv + (((size_t)win * 3 + 1) * 8 + h) * 1568;
    const unsigned short* qp = qkv + (((size_t)win * 3 + 0) * 8 + h) * 1568;
    short8 ka[4], qa[4];
#pragma unroll
    for (int f = 0; f < 4; ++f) {
      ka[f] = *(const short8*)(kp + (f * 16 + l15) * 32 + kk8);
      qa[f] = *(const short8*)(qp + (f * 16 + l15) * 32 + kk8);
    }
#pragma unroll
    for (int mf = 0; mf < 4; ++mf)
#pragma unroll
      for (int nf = 0; nf < 4; ++nf)
        s[mf][nf] = __builtin_amdgcn_mfma_f32_16x16x32_bf16(ka[mf], qa[nf], s[mf][nf], 0, 0, 0);

    unsigned D[4][4][2];
#pragma unroll
    for (int nf = 0; nf < 4; ++nf) {
      float m = -3.0e8f;
#pragma unroll
      for (int mf = 0; mf < 4; ++mf)
#pragma unroll
        for (int j = 0; j < 4; ++j) m = fmaxf(m, s[mf][nf][j]);
      m = fmaxf(m, __shfl_xor(m, 16));
      m = fmaxf(m, __shfl_xor(m, 32));
      float sum = 0.f;
#pragma unroll
      for (int mf = 0; mf < 4; ++mf)
#pragma unroll
        for (int j = 0; j < 4; ++j) {
          float e = __expf(s[mf][nf][j] - m);
          s[mf][nf][j] = e; sum += e;
        }
      sum += __shfl_xor(sum, 16);
      sum += __shfl_xor(sum, 32);
      float inv = 1.0f / sum;
#pragma unroll
      for (int mf = 0; mf < 4; ++mf) {
        D[mf][nf][0] = pk2(s[mf][nf][0] * inv, s[mf][nf][1] * inv);
        D[mf][nf][1] = pk2(s[mf][nf][2] * inv, s[mf][nf][3] * inv);
      }
    }

    f32x4 o[8];
#pragma unroll
    for (int i = 0; i < 8; ++i) o[i] = (f32x4){0.f, 0.f, 0.f, 0.f};
#pragma unroll
    for (int ks = 0; ks < 2; ++ks) {
      short8 vb[2];
#pragma unroll
      for (int dt = 0; dt < 2; ++dt)
        vb[dt] = *(const short8*)(VT8 + h * 2304 + (dt * 16 + l15) * 72 + ks * 32 + kk8);
#pragma unroll
      for (int qt = 0; qt < 4; ++qt) {
        int a0 = __shfl((int)D[2*ks+0][qt][0], sA), a1 = __shfl((int)D[2*ks+1][qt][0], sA);
        int b0 = __shfl((int)D[2*ks+0][qt][1], sA), b1 = __shfl((int)D[2*ks+1][qt][1], sA);
        int c0 = __shfl((int)D[2*ks+0][qt][0], sB), c1 = __shfl((int)D[2*ks+1][qt][0], sB);
        int e0 = __shfl((int)D[2*ks+0][qt][1], sB), e1 = __shfl((int)D[2*ks+1][qt][1], sB);
        I4S8 u;
        u.i.x = hi ? a1 : a0;
        u.i.y = hi ? b1 : b0;
        u.i.z = hi ? c1 : c0;
        u.i.w = hi ? e1 : e0;
#pragma unroll
        for (int dt = 0; dt < 2; ++dt)
          o[qt * 2 + dt] = __builtin_amdgcn_mfma_f32_16x16x32_bf16(u.s, vb[dt], o[qt * 2 + dt], 0, 0, 0);
      }
    }
#pragma unroll
    for (int f = 0; f < 8; ++f) {
      ob[hh][f][0] = pk2(o[f][0], o[f][1]);
      ob[hh][f][1] = pk2(o[f][2], o[f][3]);
    }
  }
  __syncthreads();

  unsigned short* Ow = qkv + (size_t)win * 37632;
#pragma unroll
  for (int hh = 0; hh < 2; ++hh) {
    int h = w + hh * 4;
#pragma unroll
    for (int qt = 0; qt < 4; ++qt)
#pragma unroll
      for (int j = 0; j < 4; ++j) {
        int q = qt * 16 + rj + j;
        if (q < 49) {
#pragma unroll
          for (int dt = 0; dt < 2; ++dt)
            Ow[q * 256 + h * 32 + dt * 16 + l15] =
                (unsigned short)(ob[hh][qt * 2 + dt][j >> 1] >> ((j & 1) * 16));
        }
      }
  }
}

// ---------------- k_proj: x1 = x + LN(O @ Wp^T + b), N-split waves, cross-wave LN ----------------
__launch_bounds__(256)
__global__ void k_proj(const unsigned short* __restrict__ qkvO, const unsigned short* __restrict__ wp,
                       const float* __restrict__ proj_b, const float* __restrict__ n1w,
                       const float* __restrict__ n1b, const float* __restrict__ x,
                       float* __restrict__ x1) {
  const int mb = xcd_swz(blockIdx.x, gridDim.x);
  const int t = threadIdx.x, lane = t & 63, w = t >> 6;
  const int wr = w & 1, wc = w >> 1;   // row-half (32 rows), col-half (128 cols)
  const int l15 = lane & 15, g = lane >> 4, rj = g << 2;

  __shared__ __align__(16) unsigned short As[64 * 64];    // 8192 B
  __shared__ __align__(16) unsigned short Bs[256 * 64];   // 32768 B
  __shared__ float RED[64][2][2];                          // {s,s2} per col-half

  f32x4 acc[2][8];
#pragma unroll
  for (int mf = 0; mf < 2; ++mf)
#pragma unroll
    for (int nf = 0; nf < 8; ++nf) acc[mf][nf] = (f32x4){0.f, 0.f, 0.f, 0.f};

  const int rl = lane >> 3;
  const int ca = (lane & 7) ^ rl;

  for (int kb = 0; kb < 4; ++kb) {
    __syncthreads();
#pragma unroll
    for (int cc = 0; cc < 2; ++cc) {
      int rloc = w * 16 + cc * 8 + rl;
      int row_g = mb * 64 + rloc;
      int win = row_g / 49, r = row_g - win * 49;
      stage8(qkvO + (size_t)win * 37632 + r * 256 + kb * 64 + ca * 8,
             As + (w * 16 + cc * 8) * 64, lane);
    }
#pragma unroll
    for (int cc = 0; cc < 4; ++cc) {
      int rloc = w * 64 + cc * 8 + rl;
      stage8(wp + (size_t)rloc * 256 + kb * 64 + ca * 8, Bs + (w * 64 + cc * 8) * 64, lane);
      int rloc2 = rloc + 32;
      stage8(wp + (size_t)rloc2 * 256 + kb * 64 + ca * 8, Bs + (w * 64 + cc * 8 + 32) * 64, lane);
    }
    __syncthreads();
    // N-split compute: 2 A-reads + 8 B-reads per ks
#pragma unroll
    for (int ks = 0; ks < 2; ++ks) {
      short8 a_[2], b_[8];
#pragma unroll
      for (int mf = 0; mf < 2; ++mf) {
        int R = wr * 32 + mf * 16 + l15;
        a_[mf] = *(const short8*)(As + R * 64 + (((ks * 4 + g) ^ (R & 7)) << 3));
      }
#pragma unroll
      for (int nf = 0; nf < 8; ++nf) {
        int Rb = wc * 128 + nf * 16 + l15;
        b_[nf] = *(const short8*)(Bs + Rb * 64 + (((ks * 4 + g) ^ (Rb & 7)) << 3));
      }
#pragma unroll
      for (int mf = 0; mf < 2; ++mf)
#pragma unroll
        for (int nf = 0; nf < 8; ++nf)
          acc[mf][nf] = __builtin_amdgcn_mfma_f32_16x16x32_bf16(a_[mf], b_[nf], acc[mf][nf], 0, 0, 0);
    }
  }
  // bias + partial row sums over this wave's 128 cols
#pragma unroll
  for (int nf = 0; nf < 8; ++nf) {
    float bias = proj_b[wc * 128 + nf * 16 + l15];
#pragma unroll
    for (int mf = 0; mf < 2; ++mf)
#pragma unroll
      for (int j = 0; j < 4; ++j) acc[mf][nf][j] += bias;
  }
#pragma unroll
  for (int mf = 0; mf < 2; ++mf)
#pragma unroll
    for (int j = 0; j < 4; ++j) {
      float s = 0.f, s2 = 0.f;
#pragma unroll
      for (int nf = 0; nf < 8; ++nf) {
        float v = acc[mf][nf][j];
        s += v; s2 += v * v;
      }
      s += __shfl_xor(s, 1);  s += __shfl_xor(s, 2);  s += __shfl_xor(s, 4);  s += __shfl_xor(s, 8);
      s2 += __shfl_xor(s2, 1); s2 += __shfl_xor(s2, 2); s2 += __shfl_xor(s2, 4); s2 += __shfl_xor(s2, 8);
      if (l15 == 0) {
        int row = wr * 32 + mf * 16 + rj + j;
        RED[row][wc][0] = s;
        RED[row][wc][1] = s2;
      }
    }
  __syncthreads();
#pragma unroll
  for (int mf = 0; mf < 2; ++mf)
#pragma unroll
    for (int j = 0; j < 4; ++j) {
      int row = wr * 32 + mf * 16 + rj + j;
      float ts = RED[row][0][0] + RED[row][1][0];
      float ts2 = RED[row][0][1] + RED[row][1][1];
      float mu = ts * (1.0f / 256.0f);
      float var = ts2 * (1.0f / 256.0f) - mu * mu;
      float rs = rsqrtf(var + 1e-5f);
      int row_g = mb * 64 + row;
      int win = row_g / 49, r = row_g - win * 49;
      int b = win >> 6, wi = (win >> 3) & 7, wj = win & 7;
      int i2 = r / 7, j2 = r - i2 * 7;
      int ho = (wi * 7 + i2 + 3) % 56, wo = (wj * 7 + j2 + 3) % 56;
      size_t base = (size_t)(b * 3136 + ho * 56 + wo) * 256;
#pragma unroll
      for (int nf = 0; nf < 8; ++nf) {
        int col = wc * 128 + nf * 16 + l15;
        float xv = x[base + col];
        x1[base + col] = xv + (acc[mf][nf][j] - mu) * rs * n1w[col] + n1b[col];
      }
    }
}

// ---------------- k_fc1: H = gelu(xb @ W1^T + b1), GLL-staged, direct scatter ----------------
__launch_bounds__(256)
__global__ void k_fc1(const unsigned short* __restrict__ xb, const unsigned short* __restrict__ w1,
                      const float* __restrict__ b1, unsigned short* __restrict__ Hbuf, int r0) {
  const int mb = xcd_swz(blockIdx.x, gridDim.x), nb = blockIdx.y;
  const int t = threadIdx.x, lane = t & 63, w = t >> 6;
  const int wm = w >> 1, wn = w & 1;
  const int l15 = lane & 15, g = lane >> 4, rj = g << 2;

  __shared__ __align__(16) unsigned short As[128 * 64];   // 16384 B
  __shared__ __align__(16) unsigned short Bs[128 * 64];   // 16384 B

  f32x4 acc[4][4];
#pragma unroll
  for (int mf = 0; mf < 4; ++mf)
#pragma unroll
    for (int nf = 0; nf < 4; ++nf) acc[mf][nf] = (f32x4){0.f, 0.f, 0.f, 0.f};

  const int row_g0 = r0 + mb * 128;
  const int rl = lane >> 3;
  const int ca = (lane & 7) ^ rl;

  for (int kb = 0; kb < 4; ++kb) {
    __syncthreads();
#pragma unroll
    for (int cc = 0; cc < 4; ++cc) {
      int r = w * 32 + cc * 8 + rl;
      stage8(xb + (size_t)(row_g0 + r) * 256 + kb * 64 + ca * 8, As + (w * 32 + cc * 8) * 64, lane);
      stage8(w1 + (size_t)(nb * 128 + r) * 256 + kb * 64 + ca * 8, Bs + (w * 32 + cc * 8) * 64, lane);
    }
    __syncthreads();
#pragma unroll
    for (int ks = 0; ks < 2; ++ks) {
      short8 a_[4], b_[4];
#pragma unroll
      for (int mf = 0; mf < 4; ++mf) {
        int R = wm * 64 + mf * 16 + l15;
        a_[mf] = *(const short8*)(As + R * 64 + (((ks * 4 + g) ^ (R & 7)) << 3));
      }
#pragma unroll
      for (int nf = 0; nf < 4; ++nf) {
        int R = wn * 64 + nf * 16 + l15;
        b_[nf] = *(const short8*)(Bs + R * 64 + (((ks * 4 + g) ^ (R & 7)) << 3));
      }
#pragma unroll
      for (int mf = 0; mf < 4; ++mf)
#pragma unroll
        for (int nf = 0; nf < 4; ++nf)
          acc[mf][nf] = __builtin_amdgcn_mfma_f32_16x16x32_bf16(a_[mf], b_[nf], acc[mf][nf], 0, 0, 0);
    }
  }
  // direct-scatter epilogue
#pragma unroll
  for (int mf = 0; mf < 4; ++mf)
#pragma unroll
    for (int nf = 0; nf < 4; ++nf) {
      int col = nb * 128 + wn * 64 + nf * 16 + l15;
      float bias = b1[col];
#pragma unroll
      for (int j = 0; j < 4; ++j) {
        int row = mb * 128 + wm * 64 + mf * 16 + rj + j;
        Hbuf[(size_t)row * 1024 + col] = f2b(gelu_fast(acc[mf][nf][j] + bias));
      }
    }
}

// ---------------- k_fc2: out = x1 + LN(H @ W2^T + b2), N-split waves, cross-wave LN ----------------
__launch_bounds__(256)
__global__ void k_fc2(const unsigned short* __restrict__ Hbuf, const unsigned short* __restrict__ w2,
                      const float* __restrict__ b2, const float* __restrict__ n2w,
                      const float* __restrict__ n2b, float* __restrict__ xio, int r0) {
  const int mb = xcd_swz(blockIdx.x, gridDim.x);   // 64 rows per block
  const int t = threadIdx.x, lane = t & 63, w = t >> 6;
  const int wr = w & 1, wc = w >> 1;   // row-half (32 rows), col-half (128 cols)
  const int l15 = lane & 15, g = lane >> 4, rj = g << 2;

  __shared__ __align__(16) unsigned short As[64 * 64];    // 8192 B
  __shared__ __align__(16) unsigned short Bs[256 * 64];   // 32768 B
  __shared__ float RED[64][2][2];                          // 1 KB {s,s2} per col-half

  f32x4 acc[2][8];
#pragma unroll
  for (int mf = 0; mf < 2; ++mf)
#pragma unroll
    for (int nf = 0; nf < 8; ++nf) acc[mf][nf] = (f32x4){0.f, 0.f, 0.f, 0.f};

  const int rl = lane >> 3;
  const int ca = (lane & 7) ^ rl;

  for (int kb = 0; kb < 16; ++kb) {
    __syncthreads();
#pragma unroll
    for (int cc = 0; cc < 2; ++cc) {
      int rloc = w * 16 + cc * 8 + rl;
      stage8(Hbuf + (size_t)(mb * 64 + rloc) * 1024 + kb * 64 + ca * 8,
             As + (w * 16 + cc * 8) * 64, lane);
    }
#pragma unroll
    for (int cc = 0; cc < 4; ++cc) {
      int rloc = w * 64 + cc * 8 + rl;
      stage8(w2 + (size_t)rloc * 1024 + kb * 64 + ca * 8, Bs + (w * 64 + cc * 8) * 64, lane);
      int rloc2 = rloc + 32;
      stage8(w2 + (size_t)rloc2 * 1024 + kb * 64 + ca * 8, Bs + (w * 64 + cc * 8 + 32) * 64, lane);
    }
    __syncthreads();
    // N-split compute: 2 A-reads + 8 B-reads per ks
#pragma unroll
    for (int ks = 0; ks < 2; ++ks) {
      short8 a_[2], b_[8];
#pragma unroll
      for (int mf = 0; mf < 2; ++mf) {
        int R = wr * 32 + mf * 16 + l15;
        a_[mf] = *(const short8*)(As + R * 64 + (((ks * 4 + g) ^ (R & 7)) << 3));
      }
#pragma unroll
      for (int nf = 0; nf < 8; ++nf) {
        int Rb = wc * 128 + nf * 16 + l15;
        b_[nf] = *(const short8*)(Bs + Rb * 64 + (((ks * 4 + g) ^ (Rb & 7)) << 3));
      }
#pragma unroll
      for (int mf = 0; mf < 2; ++mf)
#pragma unroll
        for (int nf = 0; nf < 8; ++nf)
          acc[mf][nf] = __builtin_amdgcn_mfma_f32_16x16x32_bf16(a_[mf], b_[nf], acc[mf][nf], 0, 0, 0);
    }
  }
  // bias + partial row sums over this wave's 128 cols
#pragma unroll
  for (int nf = 0; nf < 8; ++nf) {
    float bias = b2[wc * 128 + nf * 16 + l15];
#pragma unroll
    for (int mf = 0; mf < 2; ++mf)
#pragma unroll
      for (int j = 0; j < 4; ++j) acc[mf][nf][j] += bias;
  }
#pragma unroll
  for (int mf = 0; mf < 2; ++mf)
#pragma unroll
    for (int j = 0; j < 4; ++j) {
      float s = 0.f, s2 = 0.f;
#pragma unroll
      for (int nf = 0; nf < 8; ++nf) {
        float v = acc[mf][nf][j];
        s += v; s2 += v * v;
      }
      s += __shfl_xor(s, 1);  s += __shfl_xor(s, 2);  s += __shfl_xor(s, 4);  s += __shfl_xor(s, 8);
      s2 += __shfl_xor(s2, 1); s2 += __shfl_xor(s2, 2); s2 += __shfl_xor(s2, 4); s2 += __shfl_xor(s2, 8);
      if (l15 == 0) {
        int row = wr * 32 + mf * 16 + rj + j;
        RED[row][wc][0] = s;
        RED[row][wc][1] = s2;
      }
    }
  __syncthreads();
#pragma unroll
  for (int mf = 0; mf < 2; ++mf)
#pragma unroll
    for (int j = 0; j < 4; ++j) {
      int row = wr * 32 + mf * 16 + rj + j;
      float ts = RED[row][0][0] + RED[row][1][0];
      float ts2 = RED[row][0][1] + RED[row][1][1];
      float mu = ts * (1.0f / 256.0f);
      float var = ts2 * (1.0f / 256.0f) - mu * mu;
      float rs = rsqrtf(var + 1e-5f);
      size_t base = (size_t)(r0 + mb * 64 + row) * 256;
#pragma unroll
      for (int nf = 0; nf < 8; ++nf) {
        int col = wc * 128 + nf * 16 + l15;
        float xv = xio[base + col];
        xio[base + col] = xv + (acc[mf][nf][j] - mu) * rs * n2w[col] + n2b[col];
      }
    }
}

extern "C" void kernel_launch(void* const* d_in, const int* in_sizes, int n_in,
                              void* d_out, int out_size, void* d_ws, size_t ws_size,
                              hipStream_t stream) {
  const float* x           = (const float*)d_in[0];
  const float* norm1_w     = (const float*)d_in[1];
  const float* norm1_b     = (const float*)d_in[2];
  const float* qkv_w       = (const float*)d_in[3];
  const float* q_bias      = (const float*)d_in[4];
  const float* v_bias      = (const float*)d_in[5];
  const float* logit_scale = (const float*)d_in[6];
  const float* cpb_w1      = (const float*)d_in[7];
  const float* cpb_b1      = (const float*)d_in[8];
  const float* cpb_w2      = (const float*)d_in[9];
  const float* proj_w      = (const float*)d_in[10];
  const float* proj_b      = (const float*)d_in[11];
  const float* norm2_w     = (const float*)d_in[12];
  const float* norm2_b     = (const float*)d_in[13];
  const float* fc1_w       = (const float*)d_in[14];
  const float* fc1_b       = (const float*)d_in[15];
  const float* fc2_w       = (const float*)d_in[16];
  const float* fc2_b       = (const float*)d_in[17];

  char* ws = (char*)d_ws;
  float*          scales  = (float*)(ws + 0);
  float*          tblg    = (float*)(ws + 64);
  unsigned short* wq      = (unsigned short*)(ws + 8192);    // dead after k_qkvg; biasT overlays
  float*          biasT   = (float*)(ws + 8192);
  unsigned short* wp      = (unsigned short*)(ws + 401408);
  unsigned short* w1b     = (unsigned short*)(ws + 532480);
  unsigned short* w2b     = (unsigned short*)(ws + 1056768);
  unsigned short* qkvbuf  = (unsigned short*)(ws + 1581056); // 77070336 B (attn phase)
  unsigned short* xb      = (unsigned short*)(ws + 1581056); // MLP phase (qkvbuf dead): 25.7MB
  unsigned short* Hbuf    = (unsigned short*)(ws + 27271168);
  float*          x1      = (float*)d_out;
  unsigned short* xw      = (unsigned short*)d_out;          // dead before k_proj writes x1

  k_misc<<<dim3(170), dim3(256), 0, stream>>>(logit_scale, cpb_w1, cpb_b1, cpb_w2, scales, tblg);
  k_cvt<<<dim3(3072), dim3(256), 0, stream>>>(qkv_w, proj_w, fc1_w, fc2_w, wq, wp, w1b, w2b);
  k_xprep<<<dim3(6272), dim3(256), 0, stream>>>(x, xw);
  k_qkvg<<<dim3(392, 3), dim3(512), 0, stream>>>(xw, wq, q_bias, v_bias, scales, qkvbuf);
  k_bias<<<dim3(128), dim3(256), 0, stream>>>(tblg, biasT);
  k_attn2<<<dim3(1024), dim3(256), 0, stream>>>(qkvbuf, biasT);
  k_proj<<<dim3(784), dim3(256), 0, stream>>>(qkvbuf, wp, proj_b, norm1_w, norm1_b, x, x1);
  k_xb<<<dim3(6272), dim3(256), 0, stream>>>(x1, xb);

  // 2-pass MLP: halve Hbuf's live footprint (51.4MB/phase) so fc2 reads rows fc1 just
  // wrote while they are still L3-resident (fc2 FETCH was 77% of Hbuf in 1-pass).
  k_fc1<<<dim3(196, 8), dim3(256), 0, stream>>>(xb, w1b, fc1_b, Hbuf, 0);
  k_fc2<<<dim3(392), dim3(256), 0, stream>>>(Hbuf, w2b, fc2_b, norm2_w, norm2_b, x1, 0);
  k_fc1<<<dim3(196, 8), dim3(256), 0, stream>>>(xb, w1b, fc1_b, Hbuf, 25088);
  k_fc2<<<dim3(392), dim3(256), 0, stream>>>(Hbuf, w2b, fc2_b, norm2_w, norm2_b, x1, 25088);
}

// Round 27
// 292.258 us; speedup vs baseline: 1.1424x; 1.0483x over previous
//
#include <hip/hip_runtime.h>
#include <hip/hip_bf16.h>

typedef __attribute__((ext_vector_type(8))) short short8;
typedef __attribute__((ext_vector_type(4))) float f32x4;

union I4S8 { int4 i; short8 s; };

#if defined(__has_builtin)
#if __has_builtin(__builtin_amdgcn_global_load_lds)
#define HAVE_GLL 1
#endif
#endif

__device__ __forceinline__ unsigned short f2b(float f) {
  union { __hip_bfloat16 h; unsigned short u; } c;
  c.h = __float2bfloat16(f);
  return c.u;
}
__device__ __forceinline__ unsigned pk2(float a, float b) {
  union { __hip_bfloat162 h2; unsigned u; } c;
  c.h2 = __hip_bfloat162{__float2bfloat16(a), __float2bfloat16(b)};
  return c.u;
}
__device__ __forceinline__ float b2f(unsigned short h) {
  return __uint_as_float(((unsigned)h) << 16);
}
// exact identity: 0.5*v*(1+tanh(c)) == v * sigmoid(2c); proven absmax-safe (round 10)
__device__ __forceinline__ float gelu_fast(float v) {
  float c2 = 1.5957691216057308f * (v + 0.044715f * v * v * v);
  return v / (1.0f + __expf(-c2));
}
// T1 XCD-aware swizzle: bijective when n%8==0 (each XCD gets a contiguous chunk)
__device__ __forceinline__ int xcd_swz(int bid, int n) {
  return ((n & 7) == 0) ? ((bid & 7) * (n >> 3) + (bid >> 3)) : bid;
}

// stage one 8-row group (BK=64 bf16) via global_load_lds with XOR pre-swizzled source.
__device__ __forceinline__ void stage8(const unsigned short* ga, unsigned short* lds_base,
                                       int lane) {
#ifdef HAVE_GLL
  __builtin_amdgcn_global_load_lds(
      (const __attribute__((address_space(1))) void*)ga,
      (__attribute__((address_space(3))) void*)lds_base, 16, 0, 0);
#else
  *(int4*)(lds_base + (lane >> 3) * 64 + (lane & 7) * 8) = *(const int4*)ga;
#endif
}

// ---------------- k_misc: parallel CPB table (169 blocks) + scales (block 169) ----------------
__global__ void k_misc(const float* __restrict__ logit_scale,
                       const float* __restrict__ w1, const float* __restrict__ b1,
                       const float* __restrict__ w2,
                       float* __restrict__ scales, float* __restrict__ tblg) {
  const int bb = blockIdx.x;
  const int t = threadIdx.x;
  if (bb == 169) {
    if (t < 8) scales[t] = expf(fminf(logit_scale[t], logf(100.0f)));
    return;
  }
  __shared__ float red[4][8];
  int a = bb / 13, b = bb % 13;
  float ra = (float)(a - 6) * (8.0f / 6.0f);
  float rb = (float)(b - 6) * (8.0f / 6.0f);
  float sa = (ra > 0.f) ? 1.f : ((ra < 0.f) ? -1.f : 0.f);
  float sb = (rb > 0.f) ? 1.f : ((rb < 0.f) ? -1.f : 0.f);
  float t0 = sa * log2f(fabsf(ra) + 1.0f) / 3.0f;
  float t1 = sb * log2f(fabsf(rb) + 1.0f) / 3.0f;
  float acc[8];
#pragma unroll
  for (int hh = 0; hh < 8; ++hh) acc[hh] = 0.f;
#pragma unroll
  for (int jj = 0; jj < 2; ++jj) {
    int j = t + jj * 256;
    float hv = fmaxf(w1[2 * j] * t0 + w1[2 * j + 1] * t1 + b1[j], 0.0f);
#pragma unroll
    for (int hh = 0; hh < 8; ++hh) acc[hh] += w2[hh * 512 + j] * hv;
  }
#pragma unroll
  for (int hh = 0; hh < 8; ++hh) {
    acc[hh] += __shfl_xor(acc[hh], 1);
    acc[hh] += __shfl_xor(acc[hh], 2);
    acc[hh] += __shfl_xor(acc[hh], 4);
    acc[hh] += __shfl_xor(acc[hh], 8);
    acc[hh] += __shfl_xor(acc[hh], 16);
    acc[hh] += __shfl_xor(acc[hh], 32);
  }
  if ((t & 63) == 0) {
#pragma unroll
    for (int hh = 0; hh < 8; ++hh) red[t >> 6][hh] = acc[hh];
  }
  __syncthreads();
  if (t < 8) tblg[bb * 8 + t] = red[0][t] + red[1][t] + red[2][t] + red[3][t];
}

// ---------------- k_bias: biasT[h][k][q] padded 64x64, pad=-3e8 ----------------
__global__ void k_bias(const float* __restrict__ tblg, float* __restrict__ biasT) {
  int idx = blockIdx.x * 256 + threadIdx.x;   // 8*64*64 = 32768
  int h = idx >> 12, rem = idx & 4095, k = rem >> 6, q = rem & 63;
  float v;
  if (k >= 49 || q >= 49) {
    v = -3.0e8f;
  } else {
    int e = (q / 7 - k / 7 + 6) * 13 + (q % 7 - k % 7 + 6);
    float r = tblg[e * 8 + h];
    v = 16.0f / (1.0f + expf(-r));
  }
  biasT[idx] = v;
}

// ---------------- k_cvt: weights fp32 -> bf16 ----------------
__global__ void k_cvt(const float* __restrict__ qkv_w, const float* __restrict__ proj_w,
                      const float* __restrict__ fc1_w, const float* __restrict__ fc2_w,
                      unsigned short* __restrict__ wq, unsigned short* __restrict__ wp,
                      unsigned short* __restrict__ w1, unsigned short* __restrict__ w2) {
  int i = blockIdx.x * 256 + threadIdx.x;
  if (i < 196608) wq[i] = f2b(qkv_w[i]);
  else if (i < 262144) wp[i - 196608] = f2b(proj_w[i - 196608]);
  else if (i < 524288) w1[i - 262144] = f2b(fc1_w[i - 262144]);
  else w2[i - 524288] = f2b(fc2_w[i - 524288]);
}

// ---------------- k_xprep: shifted-window gather x -> xw[50176][256] bf16 ----------------
__global__ void k_xprep(const float* __restrict__ x, unsigned short* __restrict__ xw) {
  int id = blockIdx.x * 256 + threadIdx.x;
  int row = id >> 5, c8 = (id & 31) << 3;
  int win = row / 49, r = row - win * 49;
  int b = win >> 6, wi = (win >> 3) & 7, wj = win & 7;
  int i = r / 7, j = r - i * 7;
  int ho = (wi * 7 + i + 3) % 56;
  int wo = (wj * 7 + j + 3) % 56;
  const float* src = x + (size_t)(b * 3136 + ho * 56 + wo) * 256 + c8;
  float4 f0 = *(const float4*)(src);
  float4 f1 = *(const float4*)(src + 4);
  int4 pk;
  pk.x = pk2(f0.x, f0.y);
  pk.y = pk2(f0.z, f0.w);
  pk.z = pk2(f1.x, f1.y);
  pk.w = pk2(f1.z, f1.w);
  *(int4*)(xw + (size_t)row * 256 + c8) = pk;
}

// ---------------- k_xb: x1 f32 -> xb bf16 (row-linear) ----------------
__global__ void k_xb(const float* __restrict__ x1, unsigned short* __restrict__ xb) {
  int id = blockIdx.x * 256 + threadIdx.x;
  size_t off = (size_t)id << 3;
  const float* src = x1 + off;
  float4 f0 = *(const float4*)(src);
  float4 f1 = *(const float4*)(src + 4);
  int4 pk;
  pk.x = pk2(f0.x, f0.y);
  pk.y = pk2(f0.z, f0.w);
  pk.z = pk2(f1.x, f1.y);
  pk.w = pk2(f1.z, f1.w);
  *(int4*)(xb + off) = pk;
}

// ---------------- k_qkvg: 128x256 tile, swapped-operand MFMA (features row-indexed) ----------------
// acc[nf][mf] = mfma(b_, a_): row = feature = wn*64+nf*16+rj+j, col = token = ...+l15.
// Norm over a head's 32 features: per-thread partial (8 vals) + shfl_xor(16,32) across g.
// Store: 4 consecutive features per thread -> int2 (4 ushorts) packed stores.
__launch_bounds__(512)
__global__ void k_qkvg(const unsigned short* __restrict__ xw, const unsigned short* __restrict__ wq,
                       const float* __restrict__ q_bias, const float* __restrict__ v_bias,
                       const float* __restrict__ scales, unsigned short* __restrict__ qkv) {
  const int mb = xcd_swz(blockIdx.x, gridDim.x), nb = blockIdx.y;   // 392 x 3
  const int t = threadIdx.x, lane = t & 63, w = t >> 6;   // 8 waves
  const int wm = w >> 2, wn = w & 3;                      // 2 (M=token) x 4 (N=feature)
  const int l15 = lane & 15, g = lane >> 4, rj = g << 2;

  __shared__ __align__(16) unsigned short As[128 * 64];   // 16384 B
  __shared__ __align__(16) unsigned short Bs[256 * 64];   // 32768 B

  f32x4 acc[4][4];   // [nf][mf]
#pragma unroll
  for (int nf = 0; nf < 4; ++nf)
#pragma unroll
    for (int mf = 0; mf < 4; ++mf) acc[nf][mf] = (f32x4){0.f, 0.f, 0.f, 0.f};

  const int rl = lane >> 3;
  const int ca = (lane & 7) ^ rl;

  for (int kb = 0; kb < 4; ++kb) {
    __syncthreads();
#pragma unroll
    for (int i = 0; i < 6; ++i) {
      int gidx = w * 6 + i;
      if (gidx < 16) {
        int r = gidx * 8 + rl;
        stage8(xw + (size_t)(mb * 128 + r) * 256 + kb * 64 + ca * 8, As + gidx * 8 * 64, lane);
      } else {
        int gb = gidx - 16;
        int r = gb * 8 + rl;
        stage8(wq + (size_t)(nb * 256 + r) * 256 + kb * 64 + ca * 8, Bs + gb * 8 * 64, lane);
      }
    }
    __syncthreads();
#pragma unroll
    for (int ks = 0; ks < 2; ++ks) {
      short8 a_[4], b_[4];
#pragma unroll
      for (int mf = 0; mf < 4; ++mf) {
        int R = wm * 64 + mf * 16 + l15;
        a_[mf] = *(const short8*)(As + R * 64 + (((ks * 4 + g) ^ (R & 7)) << 3));
      }
#pragma unroll
      for (int nf = 0; nf < 4; ++nf) {
        int R = wn * 64 + nf * 16 + l15;
        b_[nf] = *(const short8*)(Bs + R * 64 + (((ks * 4 + g) ^ (R & 7)) << 3));
      }
#pragma unroll
      for (int nf = 0; nf < 4; ++nf)
#pragma unroll
        for (int mf = 0; mf < 4; ++mf)
          acc[nf][mf] = __builtin_amdgcn_mfma_f32_16x16x32_bf16(b_[nf], a_[mf], acc[nf][mf], 0, 0, 0);
    }
  }

  const int which = nb;
  // bias: feature f = wn*64 + nf*16 + rj + j  (j indexes the f32x4 regs)
  if (which != 1) {
    const float* bp = (which == 0) ? q_bias : v_bias;
#pragma unroll
    for (int nf = 0; nf < 4; ++nf) {
      float4 b4 = *(const float4*)(bp + wn * 64 + nf * 16 + rj);
#pragma unroll
      for (int mf = 0; mf < 4; ++mf) {
        acc[nf][mf][0] += b4.x; acc[nf][mf][1] += b4.y;
        acc[nf][mf][2] += b4.z; acc[nf][mf][3] += b4.w;
      }
    }
  }
  // cosine norm per (token, head): sum of squares over 32 features = per-thread 8 vals + g-reduce
  if (which < 2) {
#pragma unroll
    for (int mf = 0; mf < 4; ++mf)
#pragma unroll
      for (int p = 0; p < 2; ++p) {
        float ss = 0.f;
#pragma unroll
        for (int q2 = 0; q2 < 2; ++q2)
#pragma unroll
          for (int j = 0; j < 4; ++j) {
            float v = acc[2 * p + q2][mf][j];
            ss += v * v;
          }
        ss += __shfl_xor(ss, 16);
        ss += __shfl_xor(ss, 32);
        float inv = 1.0f / fmaxf(sqrtf(ss), 1e-12f);
        if (which == 0) inv *= scales[wn * 2 + p];
#pragma unroll
        for (int q2 = 0; q2 < 2; ++q2)
#pragma unroll
          for (int j = 0; j < 4; ++j) acc[2 * p + q2][mf][j] *= inv;
      }
  }
  // packed scatter to [win][3][head][49][32]: 4 consecutive features -> one int2 per (mf,nf)
#pragma unroll
  for (int mf = 0; mf < 4; ++mf) {
    int row_g = mb * 128 + wm * 64 + mf * 16 + l15;
    int win = row_g / 49, r = row_g - win * 49;
    size_t base = (((size_t)win * 3 + which) * 8) * 1568;
#pragma unroll
    for (int nf = 0; nf < 4; ++nf) {
      int h = wn * 2 + (nf >> 1), d0 = (nf & 1) * 16 + rj;
      int2 u;
      u.x = (int)pk2(acc[nf][mf][0], acc[nf][mf][1]);
      u.y = (int)pk2(acc[nf][mf][2], acc[nf][mf][3]);
      *(int2*)(qkv + base + (size_t)h * 1568 + r * 32 + d0) = u;
    }
  }
}

// ---------------- k_attn2: attention only; O overwrites the q-slice as [49][256] ----------------
__launch_bounds__(256, 4)
__global__ void k_attn2(unsigned short* __restrict__ qkv, const float* __restrict__ biasT) {
  const int win = blockIdx.x;
  const int wi = (win >> 3) & 7, wj = win & 7;
  const int t = threadIdx.x, lane = t & 63, w = t >> 6;
  const int l15 = lane & 15, g = lane >> 4;
  const int kk8 = g << 3, rj = g << 2;

  __shared__ __align__(16) unsigned short VT8[8 * 32 * 72];   // 36864 B

  const int vi = (wi == 7) ? 1 : 0, vj = (wj == 7) ? 1 : 0;

  for (int idx = t; idx < 392; idx += 256) {
    int h = idx / 49, r = idx % 49;
    const unsigned short* vp = qkv + ((((size_t)win * 3 + 2) * 8 + h) * 49 + r) * 32;
    unsigned short vv[32];
    *(int4*)(vv + 0)  = *(const int4*)(vp + 0);
    *(int4*)(vv + 8)  = *(const int4*)(vp + 8);
    *(int4*)(vv + 16) = *(const int4*)(vp + 16);
    *(int4*)(vv + 24) = *(const int4*)(vp + 24);
    unsigned short* dst = VT8 + h * 2304;
#pragma unroll
    for (int d = 0; d < 32; ++d) dst[d * 72 + r] = vv[d];
  }
  for (int idx = t; idx < 3840; idx += 256) {
    int h = idx / 480, rem = idx % 480, d = rem / 15, r = 49 + rem % 15;
    VT8[h * 2304 + d * 72 + r] = 0;
  }
  __syncthreads();

  const int sA = l15 + ((g & 1) << 5);
  const int sB = sA + 16;
  const bool hi = ((g >> 1) & 1) != 0;

  unsigned ob[2][8][2];
  for (int hh = 0; hh < 2; ++hh) {
    const int h = w + hh * 4;
    const float* bT = biasT + (size_t)h * 4096;
    f32x4 s[4][4];
#pragma unroll
    for (int mf = 0; mf < 4; ++mf)
#pragma unroll
      for (int nf = 0; nf < 4; ++nf)
#pragma unroll
        for (int j = 0; j < 4; ++j)
          s[mf][nf][j] = bT[(mf * 16 + rj + j) * 64 + nf * 16 + l15];
    if (vi | vj) {
      int rq[4];
#pragma unroll
      for (int nf = 0; nf < 4; ++nf) {
        int q = nf * 16 + l15, qi = q / 7, qj = q - qi * 7;
        int aq = vi ? (qi < 4 ? 1 : 2) : 0;
        int bq = vj ? (qj < 4 ? 1 : 2) : 0;
        rq[nf] = aq * 3 + bq;
      }
#pragma unroll
      for (int mf = 0; mf < 4; ++mf)
#pragma unroll
        for (int j = 0; j < 4; ++j) {
          int k = mf * 16 + rj + j, ki = k / 7, kj = k - ki * 7;
          int ak = vi ? (ki < 4 ? 1 : 2) : 0;
          int bk = vj ? (kj < 4 ? 1 : 2) : 0;
          int rk = ak * 3 + bk;
#pragma unroll
          for (int nf = 0; nf < 4; ++nf)
            if (rq[nf] != rk) s[mf][nf][j] -= 100.0f;
        }
    }
    const unsigned short* kp = qkv + (((size_t)win * 3 + 1) * 8 + h) * 1568;
    const unsigned short* qp = qkv + (((size_t)win * 3 + 0) * 8 + h) * 1568;
    short8 ka[4], qa[4];
#pragma unroll
    for (int f = 0; f < 4; ++f) {
      ka[f] = *(const short8*)(kp + (f * 16 + l15) * 32 + kk8);
      qa[f] = *(const short8*)(qp + (f * 16 + l15) * 32 + kk8);
    }
#pragma unroll
    for (int mf = 0; mf < 4; ++mf)
#pragma unroll
      for (int nf = 0; nf < 4; ++nf)
        s[mf][nf] = __builtin_amdgcn_mfma_f32_16x16x32_bf16(ka[mf], qa[nf], s[mf][nf], 0, 0, 0);

    unsigned D[4][4][2];
#pragma unroll
    for (int nf = 0; nf < 4; ++nf) {
      float m = -3.0e8f;
#pragma unroll
      for (int mf = 0; mf < 4; ++mf)
#pragma unroll
        for (int j = 0; j < 4; ++j) m = fmaxf(m, s[mf][nf][j]);
      m = fmaxf(m, __shfl_xor(m, 16));
      m = fmaxf(m, __shfl_xor(m, 32));
      float sum = 0.f;
#pragma unroll
      for (int mf = 0; mf < 4; ++mf)
#pragma unroll
        for (int j = 0; j < 4; ++j) {
          float e = __expf(s[mf][nf][j] - m);
          s[mf][nf][j] = e; sum += e;
        }
      sum += __shfl_xor(sum, 16);
      sum += __shfl_xor(sum, 32);
      float inv = 1.0f / sum;
#pragma unroll
      for (int mf = 0; mf < 4; ++mf) {
        D[mf][nf][0] = pk2(s[mf][nf][0] * inv, s[mf][nf][1] * inv);
        D[mf][nf][1] = pk2(s[mf][nf][2] * inv, s[mf][nf][3] * inv);
      }
    }

    f32x4 o[8];
#pragma unroll
    for (int i = 0; i < 8; ++i) o[i] = (f32x4){0.f, 0.f, 0.f, 0.f};
#pragma unroll
    for (int ks = 0; ks < 2; ++ks) {
      short8 vb[2];
#pragma unroll
      for (int dt = 0; dt < 2; ++dt)
        vb[dt] = *(const short8*)(VT8 + h * 2304 + (dt * 16 + l15) * 72 + ks * 32 + kk8);
#pragma unroll
      for (int qt = 0; qt < 4; ++qt) {
        int a0 = __shfl((int)D[2*ks+0][qt][0], sA), a1 = __shfl((int)D[2*ks+1][qt][0], sA);
        int b0 = __shfl((int)D[2*ks+0][qt][1], sA), b1 = __shfl((int)D[2*ks+1][qt][1], sA);
        int c0 = __shfl((int)D[2*ks+0][qt][0], sB), c1 = __shfl((int)D[2*ks+1][qt][0], sB);
        int e0 = __shfl((int)D[2*ks+0][qt][1], sB), e1 = __shfl((int)D[2*ks+1][qt][1], sB);
        I4S8 u;
        u.i.x = hi ? a1 : a0;
        u.i.y = hi ? b1 : b0;
        u.i.z = hi ? c1 : c0;
        u.i.w = hi ? e1 : e0;
#pragma unroll
        for (int dt = 0; dt < 2; ++dt)
          o[qt * 2 + dt] = __builtin_amdgcn_mfma_f32_16x16x32_bf16(u.s, vb[dt], o[qt * 2 + dt], 0, 0, 0);
      }
    }
#pragma unroll
    for (int f = 0; f < 8; ++f) {
      ob[hh][f][0] = pk2(o[f][0], o[f][1]);
      ob[hh][f][1] = pk2(o[f][2], o[f][3]);
    }
  }
  __syncthreads();

  unsigned short* Ow = qkv + (size_t)win * 37632;
#pragma unroll
  for (int hh = 0; hh < 2; ++hh) {
    int h = w + hh * 4;
#pragma unroll
    for (int qt = 0; qt < 4; ++qt)
#pragma unroll
      for (int j = 0; j < 4; ++j) {
        int q = qt * 16 + rj + j;
        if (q < 49) {
#pragma unroll
          for (int dt = 0; dt < 2; ++dt)
            Ow[q * 256 + h * 32 + dt * 16 + l15] =
                (unsigned short)(ob[hh][qt * 2 + dt][j >> 1] >> ((j & 1) * 16));
        }
      }
  }
}

// ---------------- k_proj: x1 = x + LN(O @ Wp^T + b), N-split waves, cross-wave LN ----------------
__launch_bounds__(256)
__global__ void k_proj(const unsigned short* __restrict__ qkvO, const unsigned short* __restrict__ wp,
                       const float* __restrict__ proj_b, const float* __restrict__ n1w,
                       const float* __restrict__ n1b, const float* __restrict__ x,
                       float* __restrict__ x1) {
  const int mb = xcd_swz(blockIdx.x, gridDim.x);
  const int t = threadIdx.x, lane = t & 63, w = t >> 6;
  const int wr = w & 1, wc = w >> 1;   // row-half (32 rows), col-half (128 cols)
  const int l15 = lane & 15, g = lane >> 4, rj = g << 2;

  __shared__ __align__(16) unsigned short As[64 * 64];    // 8192 B
  __shared__ __align__(16) unsigned short Bs[256 * 64];   // 32768 B
  __shared__ float RED[64][2][2];                          // {s,s2} per col-half

  f32x4 acc[2][8];
#pragma unroll
  for (int mf = 0; mf < 2; ++mf)
#pragma unroll
    for (int nf = 0; nf < 8; ++nf) acc[mf][nf] = (f32x4){0.f, 0.f, 0.f, 0.f};

  const int rl = lane >> 3;
  const int ca = (lane & 7) ^ rl;

  for (int kb = 0; kb < 4; ++kb) {
    __syncthreads();
#pragma unroll
    for (int cc = 0; cc < 2; ++cc) {
      int rloc = w * 16 + cc * 8 + rl;
      int row_g = mb * 64 + rloc;
      int win = row_g / 49, r = row_g - win * 49;
      stage8(qkvO + (size_t)win * 37632 + r * 256 + kb * 64 + ca * 8,
             As + (w * 16 + cc * 8) * 64, lane);
    }
#pragma unroll
    for (int cc = 0; cc < 4; ++cc) {
      int rloc = w * 64 + cc * 8 + rl;
      stage8(wp + (size_t)rloc * 256 + kb * 64 + ca * 8, Bs + (w * 64 + cc * 8) * 64, lane);
      int rloc2 = rloc + 32;
      stage8(wp + (size_t)rloc2 * 256 + kb * 64 + ca * 8, Bs + (w * 64 + cc * 8 + 32) * 64, lane);
    }
    __syncthreads();
    // N-split compute: 2 A-reads + 8 B-reads per ks
#pragma unroll
    for (int ks = 0; ks < 2; ++ks) {
      short8 a_[2], b_[8];
#pragma unroll
      for (int mf = 0; mf < 2; ++mf) {
        int R = wr * 32 + mf * 16 + l15;
        a_[mf] = *(const short8*)(As + R * 64 + (((ks * 4 + g) ^ (R & 7)) << 3));
      }
#pragma unroll
      for (int nf = 0; nf < 8; ++nf) {
        int Rb = wc * 128 + nf * 16 + l15;
        b_[nf] = *(const short8*)(Bs + Rb * 64 + (((ks * 4 + g) ^ (Rb & 7)) << 3));
      }
#pragma unroll
      for (int mf = 0; mf < 2; ++mf)
#pragma unroll
        for (int nf = 0; nf < 8; ++nf)
          acc[mf][nf] = __builtin_amdgcn_mfma_f32_16x16x32_bf16(a_[mf], b_[nf], acc[mf][nf], 0, 0, 0);
    }
  }
  // bias + partial row sums over this wave's 128 cols
#pragma unroll
  for (int nf = 0; nf < 8; ++nf) {
    float bias = proj_b[wc * 128 + nf * 16 + l15];
#pragma unroll
    for (int mf = 0; mf < 2; ++mf)
#pragma unroll
      for (int j = 0; j < 4; ++j) acc[mf][nf][j] += bias;
  }
#pragma unroll
  for (int mf = 0; mf < 2; ++mf)
#pragma unroll
    for (int j = 0; j < 4; ++j) {
      float s = 0.f, s2 = 0.f;
#pragma unroll
      for (int nf = 0; nf < 8; ++nf) {
        float v = acc[mf][nf][j];
        s += v; s2 += v * v;
      }
      s += __shfl_xor(s, 1);  s += __shfl_xor(s, 2);  s += __shfl_xor(s, 4);  s += __shfl_xor(s, 8);
      s2 += __shfl_xor(s2, 1); s2 += __shfl_xor(s2, 2); s2 += __shfl_xor(s2, 4); s2 += __shfl_xor(s2, 8);
      if (l15 == 0) {
        int row = wr * 32 + mf * 16 + rj + j;
        RED[row][wc][0] = s;
        RED[row][wc][1] = s2;
      }
    }
  __syncthreads();
#pragma unroll
  for (int mf = 0; mf < 2; ++mf)
#pragma unroll
    for (int j = 0; j < 4; ++j) {
      int row = wr * 32 + mf * 16 + rj + j;
      float ts = RED[row][0][0] + RED[row][1][0];
      float ts2 = RED[row][0][1] + RED[row][1][1];
      float mu = ts * (1.0f / 256.0f);
      float var = ts2 * (1.0f / 256.0f) - mu * mu;
      float rs = rsqrtf(var + 1e-5f);
      int row_g = mb * 64 + row;
      int win = row_g / 49, r = row_g - win * 49;
      int b = win >> 6, wi = (win >> 3) & 7, wj = win & 7;
      int i2 = r / 7, j2 = r - i2 * 7;
      int ho = (wi * 7 + i2 + 3) % 56, wo = (wj * 7 + j2 + 3) % 56;
      size_t base = (size_t)(b * 3136 + ho * 56 + wo) * 256;
#pragma unroll
      for (int nf = 0; nf < 8; ++nf) {
        int col = wc * 128 + nf * 16 + l15;
        float xv = x[base + col];
        x1[base + col] = xv + (acc[mf][nf][j] - mu) * rs * n1w[col] + n1b[col];
      }
    }
}

// ---------------- k_fc1: H = gelu(xb @ W1^T + b1), GLL-staged, direct scatter ----------------
__launch_bounds__(256)
__global__ void k_fc1(const unsigned short* __restrict__ xb, const unsigned short* __restrict__ w1,
                      const float* __restrict__ b1, unsigned short* __restrict__ Hbuf, int r0) {
  const int mb = xcd_swz(blockIdx.x, gridDim.x), nb = blockIdx.y;
  const int t = threadIdx.x, lane = t & 63, w = t >> 6;
  const int wm = w >> 1, wn = w & 1;
  const int l15 = lane & 15, g = lane >> 4, rj = g << 2;

  __shared__ __align__(16) unsigned short As[128 * 64];   // 16384 B
  __shared__ __align__(16) unsigned short Bs[128 * 64];   // 16384 B

  f32x4 acc[4][4];
#pragma unroll
  for (int mf = 0; mf < 4; ++mf)
#pragma unroll
    for (int nf = 0; nf < 4; ++nf) acc[mf][nf] = (f32x4){0.f, 0.f, 0.f, 0.f};

  const int row_g0 = r0 + mb * 128;
  const int rl = lane >> 3;
  const int ca = (lane & 7) ^ rl;

  for (int kb = 0; kb < 4; ++kb) {
    __syncthreads();
#pragma unroll
    for (int cc = 0; cc < 4; ++cc) {
      int r = w * 32 + cc * 8 + rl;
      stage8(xb + (size_t)(row_g0 + r) * 256 + kb * 64 + ca * 8, As + (w * 32 + cc * 8) * 64, lane);
      stage8(w1 + (size_t)(nb * 128 + r) * 256 + kb * 64 + ca * 8, Bs + (w * 32 + cc * 8) * 64, lane);
    }
    __syncthreads();
#pragma unroll
    for (int ks = 0; ks < 2; ++ks) {
      short8 a_[4], b_[4];
#pragma unroll
      for (int mf = 0; mf < 4; ++mf) {
        int R = wm * 64 + mf * 16 + l15;
        a_[mf] = *(const short8*)(As + R * 64 + (((ks * 4 + g) ^ (R & 7)) << 3));
      }
#pragma unroll
      for (int nf = 0; nf < 4; ++nf) {
        int R = wn * 64 + nf * 16 + l15;
        b_[nf] = *(const short8*)(Bs + R * 64 + (((ks * 4 + g) ^ (R & 7)) << 3));
      }
#pragma unroll
      for (int mf = 0; mf < 4; ++mf)
#pragma unroll
        for (int nf = 0; nf < 4; ++nf)
          acc[mf][nf] = __builtin_amdgcn_mfma_f32_16x16x32_bf16(a_[mf], b_[nf], acc[mf][nf], 0, 0, 0);
    }
  }
  // direct-scatter epilogue
#pragma unroll
  for (int mf = 0; mf < 4; ++mf)
#pragma unroll
    for (int nf = 0; nf < 4; ++nf) {
      int col = nb * 128 + wn * 64 + nf * 16 + l15;
      float bias = b1[col];
#pragma unroll
      for (int j = 0; j < 4; ++j) {
        int row = mb * 128 + wm * 64 + mf * 16 + rj + j;
        Hbuf[(size_t)row * 1024 + col] = f2b(gelu_fast(acc[mf][nf][j] + bias));
      }
    }
}

// ---------------- k_fc2: out = x1 + LN(H @ W2^T + b2), N-split waves, cross-wave LN ----------------
__launch_bounds__(256)
__global__ void k_fc2(const unsigned short* __restrict__ Hbuf, const unsigned short* __restrict__ w2,
                      const float* __restrict__ b2, const float* __restrict__ n2w,
                      const float* __restrict__ n2b, float* __restrict__ xio, int r0) {
  const int mb = xcd_swz(blockIdx.x, gridDim.x);   // 64 rows per block
  const int t = threadIdx.x, lane = t & 63, w = t >> 6;
  const int wr = w & 1, wc = w >> 1;   // row-half (32 rows), col-half (128 cols)
  const int l15 = lane & 15, g = lane >> 4, rj = g << 2;

  __shared__ __align__(16) unsigned short As[64 * 64];    // 8192 B
  __shared__ __align__(16) unsigned short Bs[256 * 64];   // 32768 B
  __shared__ float RED[64][2][2];                          // 1 KB {s,s2} per col-half

  f32x4 acc[2][8];
#pragma unroll
  for (int mf = 0; mf < 2; ++mf)
#pragma unroll
    for (int nf = 0; nf < 8; ++nf) acc[mf][nf] = (f32x4){0.f, 0.f, 0.f, 0.f};

  const int rl = lane >> 3;
  const int ca = (lane & 7) ^ rl;

  for (int kb = 0; kb < 16; ++kb) {
    __syncthreads();
#pragma unroll
    for (int cc = 0; cc < 2; ++cc) {
      int rloc = w * 16 + cc * 8 + rl;
      stage8(Hbuf + (size_t)(mb * 64 + rloc) * 1024 + kb * 64 + ca * 8,
             As + (w * 16 + cc * 8) * 64, lane);
    }
#pragma unroll
    for (int cc = 0; cc < 4; ++cc) {
      int rloc = w * 64 + cc * 8 + rl;
      stage8(w2 + (size_t)rloc * 1024 + kb * 64 + ca * 8, Bs + (w * 64 + cc * 8) * 64, lane);
      int rloc2 = rloc + 32;
      stage8(w2 + (size_t)rloc2 * 1024 + kb * 64 + ca * 8, Bs + (w * 64 + cc * 8 + 32) * 64, lane);
    }
    __syncthreads();
    // N-split compute: 2 A-reads + 8 B-reads per ks
#pragma unroll
    for (int ks = 0; ks < 2; ++ks) {
      short8 a_[2], b_[8];
#pragma unroll
      for (int mf = 0; mf < 2; ++mf) {
        int R = wr * 32 + mf * 16 + l15;
        a_[mf] = *(const short8*)(As + R * 64 + (((ks * 4 + g) ^ (R & 7)) << 3));
      }
#pragma unroll
      for (int nf = 0; nf < 8; ++nf) {
        int Rb = wc * 128 + nf * 16 + l15;
        b_[nf] = *(const short8*)(Bs + Rb * 64 + (((ks * 4 + g) ^ (Rb & 7)) << 3));
      }
#pragma unroll
      for (int mf = 0; mf < 2; ++mf)
#pragma unroll
        for (int nf = 0; nf < 8; ++nf)
          acc[mf][nf] = __builtin_amdgcn_mfma_f32_16x16x32_bf16(a_[mf], b_[nf], acc[mf][nf], 0, 0, 0);
    }
  }
  // bias + partial row sums over this wave's 128 cols
#pragma unroll
  for (int nf = 0; nf < 8; ++nf) {
    float bias = b2[wc * 128 + nf * 16 + l15];
#pragma unroll
    for (int mf = 0; mf < 2; ++mf)
#pragma unroll
      for (int j = 0; j < 4; ++j) acc[mf][nf][j] += bias;
  }
#pragma unroll
  for (int mf = 0; mf < 2; ++mf)
#pragma unroll
    for (int j = 0; j < 4; ++j) {
      float s = 0.f, s2 = 0.f;
#pragma unroll
      for (int nf = 0; nf < 8; ++nf) {
        float v = acc[mf][nf][j];
        s += v; s2 += v * v;
      }
      s += __shfl_xor(s, 1);  s += __shfl_xor(s, 2);  s += __shfl_xor(s, 4);  s += __shfl_xor(s, 8);
      s2 += __shfl_xor(s2, 1); s2 += __shfl_xor(s2, 2); s2 += __shfl_xor(s2, 4); s2 += __shfl_xor(s2, 8);
      if (l15 == 0) {
        int row = wr * 32 + mf * 16 + rj + j;
        RED[row][wc][0] = s;
        RED[row][wc][1] = s2;
      }
    }
  __syncthreads();
#pragma unroll
  for (int mf = 0; mf < 2; ++mf)
#pragma unroll
    for (int j = 0; j < 4; ++j) {
      int row = wr * 32 + mf * 16 + rj + j;
      float ts = RED[row][0][0] + RED[row][1][0];
      float ts2 = RED[row][0][1] + RED[row][1][1];
      float mu = ts * (1.0f / 256.0f);
      float var = ts2 * (1.0f / 256.0f) - mu * mu;
      float rs = rsqrtf(var + 1e-5f);
      size_t base = (size_t)(r0 + mb * 64 + row) * 256;
#pragma unroll
      for (int nf = 0; nf < 8; ++nf) {
        int col = wc * 128 + nf * 16 + l15;
        float xv = xio[base + col];
        xio[base + col] = xv + (acc[mf][nf][j] - mu) * rs * n2w[col] + n2b[col];
      }
    }
}

extern "C" void kernel_launch(void* const* d_in, const int* in_sizes, int n_in,
                              void* d_out, int out_size, void* d_ws, size_t ws_size,
                              hipStream_t stream) {
  const float* x           = (const float*)d_in[0];
  const float* norm1_w     = (const float*)d_in[1];
  const float* norm1_b     = (const float*)d_in[2];
  const float* qkv_w       = (const float*)d_in[3];
  const float* q_bias      = (const float*)d_in[4];
  const float* v_bias      = (const float*)d_in[5];
  const float* logit_scale = (const float*)d_in[6];
  const float* cpb_w1      = (const float*)d_in[7];
  const float* cpb_b1      = (const float*)d_in[8];
  const float* cpb_w2      = (const float*)d_in[9];
  const float* proj_w      = (const float*)d_in[10];
  const float* proj_b      = (const float*)d_in[11];
  const float* norm2_w     = (const float*)d_in[12];
  const float* norm2_b     = (const float*)d_in[13];
  const float* fc1_w       = (const float*)d_in[14];
  const float* fc1_b       = (const float*)d_in[15];
  const float* fc2_w       = (const float*)d_in[16];
  const float* fc2_b       = (const float*)d_in[17];

  char* ws = (char*)d_ws;
  float*          scales  = (float*)(ws + 0);
  float*          tblg    = (float*)(ws + 64);
  unsigned short* wq      = (unsigned short*)(ws + 8192);    // dead after k_qkvg; biasT overlays
  float*          biasT   = (float*)(ws + 8192);
  unsigned short* wp      = (unsigned short*)(ws + 401408);
  unsigned short* w1b     = (unsigned short*)(ws + 532480);
  unsigned short* w2b     = (unsigned short*)(ws + 1056768);
  unsigned short* qkvbuf  = (unsigned short*)(ws + 1581056); // 77070336 B (attn phase)
  unsigned short* xb      = (unsigned short*)(ws + 1581056); // MLP phase (qkvbuf dead): 25.7MB
  unsigned short* Hbuf    = (unsigned short*)(ws + 27271168);
  float*          x1      = (float*)d_out;
  unsigned short* xw      = (unsigned short*)d_out;          // dead before k_proj writes x1

  k_misc<<<dim3(170), dim3(256), 0, stream>>>(logit_scale, cpb_w1, cpb_b1, cpb_w2, scales, tblg);
  k_cvt<<<dim3(3072), dim3(256), 0, stream>>>(qkv_w, proj_w, fc1_w, fc2_w, wq, wp, w1b, w2b);
  k_xprep<<<dim3(6272), dim3(256), 0, stream>>>(x, xw);
  k_qkvg<<<dim3(392, 3), dim3(512), 0, stream>>>(xw, wq, q_bias, v_bias, scales, qkvbuf);
  k_bias<<<dim3(128), dim3(256), 0, stream>>>(tblg, biasT);
  k_attn2<<<dim3(1024), dim3(256), 0, stream>>>(qkvbuf, biasT);
  k_proj<<<dim3(784), dim3(256), 0, stream>>>(qkvbuf, wp, proj_b, norm1_w, norm1_b, x, x1);
  k_xb<<<dim3(6272), dim3(256), 0, stream>>>(x1, xb);

  const size_t need_1pass = 27271168ull + 102760448ull;   // xb end + full Hbuf (130.0 MB)
  if (ws_size >= need_1pass) {
    k_fc1<<<dim3(392, 8), dim3(256), 0, stream>>>(xb, w1b, fc1_b, Hbuf, 0);
    k_fc2<<<dim3(784), dim3(256), 0, stream>>>(Hbuf, w2b, fc2_b, norm2_w, norm2_b, x1, 0);
  } else {
    k_fc1<<<dim3(196, 8), dim3(256), 0, stream>>>(xb, w1b, fc1_b, Hbuf, 0);
    k_fc2<<<dim3(392), dim3(256), 0, stream>>>(Hbuf, w2b, fc2_b, norm2_w, norm2_b, x1, 0);
    k_fc1<<<dim3(196, 8), dim3(256), 0, stream>>>(xb, w1b, fc1_b, Hbuf, 25088);
    k_fc2<<<dim3(392), dim3(256), 0, stream>>>(Hbuf, w2b, fc2_b, norm2_w, norm2_b, x1, 25088);
  }
}